// Round 11
// baseline (347.195 us; speedup 1.0000x reference)
//
#include <hip/hip_runtime.h>
#include <math.h>

#define B_SZ    2
#define L_SEQ   2048
#define D_MODEL 1024
#define D_INNER 2048
#define D_STATE 16
#define DT_RANK 64
#define MM      (B_SZ * L_SEQ)   // 4096 rows
#define NCH     64               // scan chunks (R8-proven: scan is latency-bound, needs TLP)
#define CLEN    (L_SEQ / NCH)    // 32 steps per chunk
#define PFD     8                // scan prefetch depth

typedef _Float16 h8v __attribute__((ext_vector_type(8)));
typedef _Float16 h4v __attribute__((ext_vector_type(4)));
typedef float f32x4 __attribute__((ext_vector_type(4)));

// Async global->LDS DMA, 16B per lane. LDS dest = uniform base + lane*16.
__device__ __forceinline__ void gload16(const void* g, void* l) {
    __builtin_amdgcn_global_load_lds((const __attribute__((address_space(1))) void*)g,
                                     (__attribute__((address_space(3))) void*)l, 16, 0, 0);
}

// r^(1..16) via repeated-squaring tree: depth <=4 (vs 16-deep serial fold).
__device__ __forceinline__ void pow_tree(float r1, float* rp) {
    float r2 = r1 * r1, r3 = r2 * r1, r4 = r2 * r2;
    float r8 = r4 * r4;
    rp[0] = r1;      rp[1] = r2;      rp[2] = r3;      rp[3] = r4;
    rp[4] = r4 * r1; rp[5] = r4 * r2; rp[6] = r4 * r3; rp[7] = r8;
    rp[8] = r8 * r1; rp[9] = r8 * r2; rp[10] = r8 * r3; rp[11] = r8 * r4;
    rp[12] = r8 * rp[4]; rp[13] = r8 * rp[5]; rp[14] = r8 * rp[6]; rp[15] = r8 * r8;
}

// ---------------------------------------------------------------------------
// prep: all weight transposes (fp32 -> fp16 T[N][K]) + x -> fp16 cast +
// conv_w transpose to [k][d] fp32.
// ---------------------------------------------------------------------------
__global__ __launch_bounds__(256) void prep(const float* __restrict__ x,
                                            _Float16* __restrict__ xf16,
                                            const float* __restrict__ W_in,
                                            _Float16* __restrict__ WinT,
                                            const float* __restrict__ W_x,
                                            _Float16* __restrict__ WxT,
                                            const float* __restrict__ W_dt,
                                            _Float16* __restrict__ WdtT,
                                            const float* __restrict__ W_out,
                                            _Float16* __restrict__ WoutT,
                                            const float* __restrict__ cw,
                                            float* __restrict__ cwT) {
    __shared__ float t[32][33];
    const int b = blockIdx.x;
    const float* W; _Float16* T; int K, N, tile;
    if (b < 4096)      { W = W_in;  T = WinT;  K = 1024; N = 4096; tile = b; }
    else if (b < 4288) { W = W_x;   T = WxT;   K = 2048; N = 96;   tile = b - 4096; }
    else if (b < 4416) { W = W_dt;  T = WdtT;  K = 64;   N = 2048; tile = b - 4288; }
    else if (b < 6464) { W = W_out; T = WoutT; K = 2048; N = 1024; tile = b - 4416; }
    else if (b < 10560) {
        int idx = (b - 6464) * 256 + threadIdx.x;
        float4 v = ((const float4*)x)[idx];
        h4v h = {(_Float16)v.x, (_Float16)v.y, (_Float16)v.z, (_Float16)v.w};
        *(h4v*)(xf16 + (size_t)idx * 4) = h;
        return;
    } else {
        // conv_w [2048][4] -> cwT [4][2048]
        for (int i = threadIdx.x; i < D_INNER * 4; i += 256) {
            int d = i >> 2, k = i & 3;
            cwT[k * D_INNER + d] = cw[i];
        }
        return;
    }
    const int ntx = N / 32;
    const int k0 = (tile / ntx) * 32, n0 = (tile % ntx) * 32;
    #pragma unroll
    for (int i = 0; i < 4; ++i) {
        int idx = threadIdx.x + i * 256;
        int r = idx >> 5, c = idx & 31;
        t[r][c] = W[(size_t)(k0 + r) * N + n0 + c];
    }
    __syncthreads();
    #pragma unroll
    for (int i = 0; i < 4; ++i) {
        int idx = threadIdx.x + i * 256;
        int n = idx >> 5, k = idx & 31;
        T[(size_t)(n0 + n) * K + k0 + k] = (_Float16)t[k][n];
    }
}

// ---------------------------------------------------------------------------
// K1 (R1 structure, best measured): 256x256 tile, BK=64, 8 waves (2Mx4N),
// double-buffered 2x64KiB LDS, 4 phases/K-tile x 16 MFMA.
// R1-R4 ledger: K1 family plateaus ~46us (~750 TF); drilling stopped.
// Epilogue: cols<2048 -> H (xs); cols>=2048 -> silu -> Hg (gate).
// ---------------------------------------------------------------------------
#define LDA_(mi, ks) (*(const h8v*)(smb + cb_ + rowA + (mi) * 2048 + ((ks) ? ps1 : ps0)))
#define LDB_(ni, ks) (*(const h8v*)(smb + cb_ + 32768 + rowB + (ni) * 2048 + ((ks) ? ps1 : ps0)))
#define PH(m0, m1) \
    _Pragma("unroll") \
    for (int ni = 0; ni < 4; ++ni) { \
        acc[m0][ni] = __builtin_amdgcn_mfma_f32_16x16x32_f16(aF0, bF[2 * ni],     acc[m0][ni], 0, 0, 0); \
        acc[m0][ni] = __builtin_amdgcn_mfma_f32_16x16x32_f16(aF1, bF[2 * ni + 1], acc[m0][ni], 0, 0, 0); \
        acc[m1][ni] = __builtin_amdgcn_mfma_f32_16x16x32_f16(aF2, bF[2 * ni],     acc[m1][ni], 0, 0, 0); \
        acc[m1][ni] = __builtin_amdgcn_mfma_f32_16x16x32_f16(aF3, bF[2 * ni + 1], acc[m1][ni], 0, 0, 0); \
    }

__global__ __launch_bounds__(512, 2) void gemm_k1(const _Float16* __restrict__ A,
                                                  const _Float16* __restrict__ Bt,
                                                  _Float16* __restrict__ H,
                                                  _Float16* __restrict__ Hg) {
    // 128 KiB LDS: [A buf0 | B buf0 | A buf1 | B buf1], 32 KiB each.
    __shared__ _Float16 smem[65536];
    char* smb = (char*)smem;

    const int tid  = threadIdx.x;
    const int wave = tid >> 6, lane = tid & 63;
    const int wm = wave >> 2, wn = wave & 3;       // 2 x 4 wave grid
    const int lm = lane & 15, lq = lane >> 4;
    const int bm = blockIdx.y * 256, bn = blockIdx.x * 256;

    // read addressing: 16B k-slot s at physical slot s ^ (row&7); row&7 == lm&7
    const int ps0 = ((lq)     ^ (lm & 7)) << 4;
    const int ps1 = ((lq + 4) ^ (lm & 7)) << 4;
    const int rowA = (wm * 128 + lm) << 7;         // 128 B per row (BK=64 fp16)
    const int rowB = (wn * 64 + lm) << 7;

    // staging: LDS linear (wave*4+q)*1024 + lane*16 -> logical slot = (lane&7)^(lane>>3)
    const int srow  = lane >> 3;
    const int sslot = (lane & 7) ^ srow;
    const _Float16* pA = A  + (size_t)(bm + wave * 32 + srow) * 1024 + sslot * 8;
    const _Float16* pB = Bt + (size_t)(bn + wave * 32 + srow) * 1024 + sslot * 8;
    char* dA = smb + wave * 4096;                  // + buf*65536
    char* dB = smb + 32768 + wave * 4096;

    f32x4 acc[8][4];
    #pragma unroll
    for (int i = 0; i < 8; ++i)
        #pragma unroll
        for (int j = 0; j < 4; ++j) acc[i][j] = (f32x4){0.f, 0.f, 0.f, 0.f};

    // prologue: stage K-tile 0 into buf 0
    #pragma unroll
    for (int q = 0; q < 4; ++q) {
        gload16(pA + q * 8192, dA + q * 1024);
        gload16(pB + q * 8192, dB + q * 1024);
    }
    asm volatile("s_waitcnt vmcnt(0)" ::: "memory");
    __builtin_amdgcn_s_barrier();

    int cb_ = 0;
    for (int t = 0; t < 16; ++t) {
        const int nb_ = 65536 - cb_;
        const bool pf = (t < 15);
        const size_t kn = (size_t)(t + 1) * 64;    // next K-tile element offset

        h8v aF0, aF1, aF2, aF3;
        h8v bF[8];

        // ---- phase 1: mi 0,1 | read all 8 B-frags | stage next A-tile ----
        aF0 = LDA_(0, 0); aF1 = LDA_(0, 1); aF2 = LDA_(1, 0); aF3 = LDA_(1, 1);
        #pragma unroll
        for (int ni = 0; ni < 4; ++ni) { bF[2 * ni] = LDB_(ni, 0); bF[2 * ni + 1] = LDB_(ni, 1); }
        if (pf) {
            #pragma unroll
            for (int q = 0; q < 4; ++q) gload16(pA + kn + q * 8192, dA + nb_ + q * 1024);
        }
        __builtin_amdgcn_s_barrier();
        asm volatile("s_waitcnt lgkmcnt(0)" ::: "memory");
        __builtin_amdgcn_s_setprio(1);
        PH(0, 1);
        __builtin_amdgcn_s_setprio(0);
        __builtin_amdgcn_s_barrier();

        // ---- phase 2: mi 2,3 | stage next B-tile ----
        aF0 = LDA_(2, 0); aF1 = LDA_(2, 1); aF2 = LDA_(3, 0); aF3 = LDA_(3, 1);
        if (pf) {
            #pragma unroll
            for (int q = 0; q < 4; ++q) gload16(pB + kn + q * 8192, dB + nb_ + q * 1024);
        }
        __builtin_amdgcn_s_barrier();
        asm volatile("s_waitcnt lgkmcnt(0)" ::: "memory");
        __builtin_amdgcn_s_setprio(1);
        PH(2, 3);
        __builtin_amdgcn_s_setprio(0);
        __builtin_amdgcn_s_barrier();

        // ---- phase 3: mi 4,5 ----
        aF0 = LDA_(4, 0); aF1 = LDA_(4, 1); aF2 = LDA_(5, 0); aF3 = LDA_(5, 1);
        __builtin_amdgcn_s_barrier();
        asm volatile("s_waitcnt lgkmcnt(0)" ::: "memory");
        __builtin_amdgcn_s_setprio(1);
        PH(4, 5);
        __builtin_amdgcn_s_setprio(0);
        __builtin_amdgcn_s_barrier();

        // ---- phase 4: mi 6,7 | counted A'-wait pre-bar, B' drain post-MFMA ----
        aF0 = LDA_(6, 0); aF1 = LDA_(6, 1); aF2 = LDA_(7, 0); aF3 = LDA_(7, 1);
        asm volatile("s_waitcnt vmcnt(4)" ::: "memory");   // A' (issued P1) done
        __builtin_amdgcn_s_barrier();
        asm volatile("s_waitcnt lgkmcnt(0)" ::: "memory");
        __builtin_amdgcn_s_setprio(1);
        PH(6, 7);
        __builtin_amdgcn_s_setprio(0);
        asm volatile("s_waitcnt vmcnt(0)" ::: "memory");   // B' (issued P2) done
        __builtin_amdgcn_s_barrier();                      // -> next tile visible

        cb_ = nb_;
    }

    // epilogue: staging LDS is free; per-wave 16x72 fp16 transpose chunks
    _Float16* ep = smem + wave * 2048;
    const bool gate = (bn >= 2048);
    _Float16* dst = gate ? Hg : H;
    const int cbase = bn + wn * 64 - (gate ? 2048 : 0);
    #pragma unroll
    for (int mi = 0; mi < 8; ++mi) {
        #pragma unroll
        for (int ni = 0; ni < 4; ++ni)
            #pragma unroll
            for (int r = 0; r < 4; ++r) {
                float v = acc[mi][ni][r];
                if (gate) v = v / (1.f + __expf(-v));
                ep[(lq * 4 + r) * 72 + ni * 16 + lm] = (_Float16)v;
            }
        int rowb = bm + wm * 128 + mi * 16;
        #pragma unroll
        for (int i = 0; i < 2; ++i) {
            int ch = lane + 64 * i;
            int row = ch >> 3, c8 = (ch & 7) * 8;
            *(h8v*)&dst[(size_t)(rowb + row) * 2048 + cbase + c8] =
                *(const h8v*)&ep[row * 72 + c8];
        }
    }
}
#undef LDA_
#undef LDB_
#undef PH

// ---------------------------------------------------------------------------
// fp16 MFMA GEMM, double-buffered async DMA: C = A[M][K] @ Bt[N][K]^T.
// 128x128 tile, 256 thr, 4 waves 2x2, wave 64x64 (4x4 16x16x32 frags), BK=32.
// (retained for K5)
// EPI 0: fp32 C.
// ---------------------------------------------------------------------------
template<int EPI>
__global__ __launch_bounds__(256) void gemm_f16(const _Float16* __restrict__ A,
                                                const _Float16* __restrict__ Bt,
                                                const float* __restrict__ bias,
                                                float* __restrict__ C,
                                                _Float16* __restrict__ H,
                                                _Float16* __restrict__ Hg,
                                                int M, int N, int K, int ldc) {
    __shared__ _Float16 smemh[16384];   // 32KB: staging dbuf, reused by epilogue

    const int tid = threadIdx.x;
    const int wave = tid >> 6, lane = tid & 63;
    const int bm = blockIdx.y * 128, bn = blockIdx.x * 128;

    const int lrow = lane >> 2, pc = lane & 3;
    const int ar = wave * 32 + lrow;
    const size_t gA = (size_t)(bm + ar) * K + ((pc ^ ((ar >> 1) & 3)) * 8);
    const size_t gB = (size_t)(bn + ar) * K + ((pc ^ ((ar >> 1) & 3)) * 8);
    const int lofs = (wave * 32) * 32;

    const int lm = lane & 15, lq = lane >> 4;
    const int rofs = (lq ^ ((lm >> 1) & 3)) * 8;
    const int wm = (wave >> 1) * 64, wn = (wave & 1) * 64;

    f32x4 acc[4][4];
    #pragma unroll
    for (int i = 0; i < 4; ++i)
        #pragma unroll
        for (int j = 0; j < 4; ++j) acc[i][j] = (f32x4){0.f, 0.f, 0.f, 0.f};

    // prologue: fill buffer 0  (A buf at kb*4096, B buf at 8192 + kb*4096)
    gload16(A + gA, smemh + lofs);
    gload16(A + gA + (size_t)16 * K, smemh + lofs + 16 * 32);
    gload16(Bt + gB, smemh + 8192 + lofs);
    gload16(Bt + gB + (size_t)16 * K, smemh + 8192 + lofs + 16 * 32);
    __syncthreads();

    int kb = 0;
    for (int k0 = 0; k0 < K; k0 += 32, kb ^= 1) {
        if (k0 + 32 < K) {   // issue next tile BEFORE computing this one
            int nb = kb ^ 1;
            gload16(A + gA + k0 + 32, smemh + nb * 4096 + lofs);
            gload16(A + gA + k0 + 32 + (size_t)16 * K, smemh + nb * 4096 + lofs + 16 * 32);
            gload16(Bt + gB + k0 + 32, smemh + 8192 + nb * 4096 + lofs);
            gload16(Bt + gB + k0 + 32 + (size_t)16 * K, smemh + 8192 + nb * 4096 + lofs + 16 * 32);
        }

        const _Float16* sA = smemh + kb * 4096;
        const _Float16* sB = smemh + 8192 + kb * 4096;
        h8v fa[4], fb[4];
        #pragma unroll
        for (int i = 0; i < 4; ++i) {
            fa[i] = *(const h8v*)&sA[(wm + i * 16 + lm) * 32 + rofs];
            fb[i] = *(const h8v*)&sB[(wn + i * 16 + lm) * 32 + rofs];
        }
        #pragma unroll
        for (int mi = 0; mi < 4; ++mi)
            #pragma unroll
            for (int ni = 0; ni < 4; ++ni)
                acc[mi][ni] = __builtin_amdgcn_mfma_f32_16x16x32_f16(fa[mi], fb[ni], acc[mi][ni], 0, 0, 0);
        __syncthreads();   // drains next-tile DMA; protects buffer reuse
    }
    // after final barrier all waves are done with staging LDS -> reuse it.

    if (EPI == 0) {
        float* ep = (float*)smemh + wave * 1088;   // 16 x 68 fp32 (padded)
        #pragma unroll
        for (int mi = 0; mi < 4; ++mi) {
            #pragma unroll
            for (int ni = 0; ni < 4; ++ni)
                #pragma unroll
                for (int r = 0; r < 4; ++r)
                    ep[(lq * 4 + r) * 68 + ni * 16 + lm] = acc[mi][ni][r];
            int rowb = bm + wm + mi * 16;
            #pragma unroll
            for (int i = 0; i < 4; ++i) {
                int ch = lane + 64 * i;
                int row = ch >> 4, c4 = (ch & 15) * 4;
                *(float4*)&C[(size_t)(rowb + row) * ldc + bn + wn + c4] =
                    *(const float4*)&ep[row * 68 + c4];
            }
        }
    } else {
        _Float16* ep = smemh + wave * 1152;        // 16 x 72 fp16 (padded, 16B rows)
        const bool gate = (EPI == 2) && (bn >= 2048);
        _Float16* dst = gate ? Hg : H;
        const int cb = bn + wn - (gate ? 2048 : 0);
        #pragma unroll
        for (int mi = 0; mi < 4; ++mi) {
            #pragma unroll
            for (int ni = 0; ni < 4; ++ni) {
                int col = bn + wn + ni * 16 + lm;
                #pragma unroll
                for (int r = 0; r < 4; ++r) {
                    float v = acc[mi][ni][r];
                    if (EPI == 1) {
                        float a = v + bias[col];
                        v = (a > 20.f) ? a : __logf(1.f + __expf(a));
                    } else if (gate) {
                        v = v / (1.f + __expf(-v));
                    }
                    ep[(lq * 4 + r) * 72 + ni * 16 + lm] = (_Float16)v;
                }
            }
            int rowb = bm + wm + mi * 16;
            #pragma unroll
            for (int i = 0; i < 2; ++i) {
                int ch = lane + 64 * i;
                int row = ch >> 3, c8 = (ch & 7) * 8;
                *(h8v*)&dst[(size_t)(rowb + row) * ldc + cb + c8] =
                    *(const h8v*)&ep[row * 72 + c8];
            }
        }
    }
}

// ---------------------------------------------------------------------------
// Fused xd + delta kernel (R9): per block (16 rows, 256 blocks):
//   phase 1: xd[16][96] = xch_rows @ WxT^T (4-wave K-split, LDS reduction);
//   phase 2: delta[16][2048] = softplus(xd @ WdtT^T + b_dt) (4-wave N-split).
// ---------------------------------------------------------------------------
__global__ __launch_bounds__(256) void gemm_xd_delta(const _Float16* __restrict__ xch,
                                                     const _Float16* __restrict__ WxT,
                                                     const _Float16* __restrict__ WdtT,
                                                     const float* __restrict__ b_dt,
                                                     float* __restrict__ Bm,
                                                     float* __restrict__ Cm,
                                                     _Float16* __restrict__ deltah) {
    __shared__ float sred[3][64][25];       // waves 1..3 partials (6 frags x 4), +1 pad
    __shared__ _Float16 xd16[16 * 72];      // xd rows (padded: 144B rows, 16B-aligned)
    __shared__ _Float16 epd[4][16 * 72];    // per-wave delta transpose staging
    const int tid = threadIdx.x;
    const int wave = tid >> 6, lane = tid & 63;
    const int lm = lane & 15, lq = lane >> 4;
    const int m0 = blockIdx.x * 16;

    // ---------------- phase 1: xd (K-split) ----------------
    const int kbase = wave * 512;
    const _Float16* pa = xch + (size_t)(m0 + lm) * D_INNER + kbase + lq * 8;
    const _Float16* pb = WxT + (size_t)lm * D_INNER + kbase + lq * 8;

    f32x4 acc[6];
    #pragma unroll
    for (int i = 0; i < 6; ++i) acc[i] = (f32x4){0.f, 0.f, 0.f, 0.f};

    #pragma unroll 2
    for (int it = 0; it < 16; ++it) {
        const int ko = it * 32;
        h8v fa = *(const h8v*)(pa + ko);
        #pragma unroll
        for (int nf = 0; nf < 6; ++nf) {
            h8v fb = *(const h8v*)(pb + (size_t)nf * 16 * D_INNER + ko);
            acc[nf] = __builtin_amdgcn_mfma_f32_16x16x32_f16(fa, fb, acc[nf], 0, 0, 0);
        }
    }

    if (wave != 0) {
        #pragma unroll
        for (int nf = 0; nf < 6; ++nf)
            #pragma unroll
            for (int r = 0; r < 4; ++r)
                sred[wave - 1][lane][nf * 4 + r] = acc[nf][r];
    }
    __syncthreads();
    if (wave == 0) {
        #pragma unroll
        for (int nf = 0; nf < 6; ++nf) {
            int col = nf * 16 + lm;
            #pragma unroll
            for (int r = 0; r < 4; ++r) {
                float v = ((acc[nf][r] + sred[0][lane][nf * 4 + r])
                           + sred[1][lane][nf * 4 + r]) + sred[2][lane][nf * 4 + r];
                int row = lq * 4 + r;               // block-local row
                if (nf < 4)        xd16[row * 72 + col] = (_Float16)v;
                else if (col < 80) Bm[(size_t)(m0 + row) * 16 + (col - 64)] = v;
                else               Cm[(size_t)(m0 + row) * 16 + (col - 80)] = v;
            }
        }
    }
    __syncthreads();

    // ---------------- phase 2: delta (N-split) ----------------
    h8v fa0 = *(const h8v*)&xd16[lm * 72 + lq * 8];        // k 0..31
    h8v fa1 = *(const h8v*)&xd16[lm * 72 + 32 + lq * 8];   // k 32..63
    const int nbase = wave * 512;
    _Float16* ep = epd[wave];

    #pragma unroll 1
    for (int g = 0; g < 8; ++g) {          // groups of 4 n-tiles (64 cols)
        #pragma unroll
        for (int t = 0; t < 4; ++t) {
            const int col = nbase + g * 64 + t * 16 + lm;
            const _Float16* wrow = WdtT + (size_t)col * 64;
            h8v fb0 = *(const h8v*)(wrow + lq * 8);
            h8v fb1 = *(const h8v*)(wrow + 32 + lq * 8);
            f32x4 a = __builtin_amdgcn_mfma_f32_16x16x32_f16(fa0, fb0,
                        (f32x4){0.f, 0.f, 0.f, 0.f}, 0, 0, 0);
            a = __builtin_amdgcn_mfma_f32_16x16x32_f16(fa1, fb1, a, 0, 0, 0);
            const float bv = b_dt[col];
            #pragma unroll
            for (int r = 0; r < 4; ++r) {
                float v = a[r] + bv;
                v = (v > 20.f) ? v : __logf(1.f + __expf(v));
                ep[(lq * 4 + r) * 72 + t * 16 + lm] = (_Float16)v;
            }
        }
        // wave-synchronous LDS transpose -> 16B stores
        #pragma unroll
        for (int i = 0; i < 2; ++i) {
            int ch = lane + 64 * i;
            int row = ch >> 3, c8 = (ch & 7) * 8;
            *(h8v*)&deltah[(size_t)(m0 + row) * D_INNER + nbase + g * 64 + c8] =
                *(const h8v*)&ep[row * 72 + c8];
        }
    }
}

// ---------------------------------------------------------------------------
// Depthwise causal conv (k=4) + bias + SiLU, 8 elements/thread.
// ---------------------------------------------------------------------------
__global__ __launch_bounds__(256) void conv_silu(const _Float16* __restrict__ xsh,
                                                 const float* __restrict__ cwT,
                                                 const float* __restrict__ cb,
                                                 _Float16* __restrict__ xch) {
    int idx = blockIdx.x * 256 + threadIdx.x;
    int d0 = (idx * 8) & (D_INNER - 1);
    int m  = (idx * 8) >> 11;
    int l  = m & (L_SEQ - 1);
    float acc[8];
    {
        float4 c0 = *(const float4*)&cb[d0];
        float4 c1 = *(const float4*)&cb[d0 + 4];
        acc[0] = c0.x; acc[1] = c0.y; acc[2] = c0.z; acc[3] = c0.w;
        acc[4] = c1.x; acc[5] = c1.y; acc[6] = c1.z; acc[7] = c1.w;
    }
    #pragma unroll
    for (int k = 0; k < 4; ++k) {
        int ll = l - 3 + k;
        if (ll >= 0) {
            h8v v = *(const h8v*)(xsh + (size_t)(m - 3 + k) * D_INNER + d0);
            float4 w0 = *(const float4*)&cwT[k * D_INNER + d0];
            float4 w1 = *(const float4*)&cwT[k * D_INNER + d0 + 4];
            acc[0] += (float)v[0] * w0.x; acc[1] += (float)v[1] * w0.y;
            acc[2] += (float)v[2] * w0.z; acc[3] += (float)v[3] * w0.w;
            acc[4] += (float)v[4] * w1.x; acc[5] += (float)v[5] * w1.y;
            acc[6] += (float)v[6] * w1.z; acc[7] += (float)v[7] * w1.w;
        }
    }
    h8v o;
    #pragma unroll
    for (int j = 0; j < 8; ++j) {
        float s = acc[j] / (1.f + __expf(-acc[j]));
        o[j] = (_Float16)s;
    }
    *(h8v*)(xch + (size_t)idx * 8) = o;
}

// ---------------------------------------------------------------------------
// Scan pass 1: per (b, chunk, d) chunk-local final state (h0=0) + S=sum(delta).
// Fast path uses pow_tree (R8).
// ---------------------------------------------------------------------------
__global__ __launch_bounds__(256) void scan_part1(const _Float16* __restrict__ deltah,
                                                  const _Float16* __restrict__ xch,
                                                  const float* __restrict__ Bm,
                                                  const float* __restrict__ A_log,
                                                  float* __restrict__ hlocal,
                                                  float* __restrict__ Ssum) {
    const int t = threadIdx.x;
    const int d = blockIdx.x * 256 + t;
    const int c = blockIdx.y;
    const int b = blockIdx.z;

    float An[16];
    {
        const float4* ap = (const float4*)(A_log + (size_t)d * 16);
        #pragma unroll
        for (int q = 0; q < 4; ++q) {
            float4 v = ap[q];
            An[q * 4 + 0] = -__expf(v.x); An[q * 4 + 1] = -__expf(v.y);
            An[q * 4 + 2] = -__expf(v.z); An[q * 4 + 3] = -__expf(v.w);
        }
    }
    const float An0 = An[0];
    bool fast = An0 < 0.f;
    #pragma unroll
    for (int n = 0; n < 16; ++n)
        fast = fast && (fabsf(An[n] - (float)(n + 1) * An0) < 1e-3f * fabsf(An[n]));

    __shared__ float sB[CLEN][16];
    {
        size_t l0 = (size_t)(b * L_SEQ + c * CLEN) * 16;
        #pragma unroll
        for (int i = 0; i < (CLEN * 16) / 256; ++i) {
            int idx = t + i * 256;
            sB[idx >> 4][idx & 15] = Bm[l0 + idx];
        }
    }
    __syncthreads();

    float h[16];
    #pragma unroll
    for (int n = 0; n < 16; ++n) h[n] = 0.f;
    float S = 0.f;

    size_t base = (size_t)(b * L_SEQ + c * CLEN) * D_INNER + d;
    float bd[PFD], bx[PFD];
    #pragma unroll
    for (int i = 0; i < PFD; ++i) {
        bd[i] = (float)deltah[base + (size_t)i * D_INNER];
        bx[i] = (float)xch[base + (size_t)i * D_INNER];
    }

    if (fast) {
        for (int jb = 0; jb < CLEN; jb += PFD) {
            #pragma unroll
            for (int i = 0; i < PFD; ++i) {
                int j = jb + i;
                float dv = bd[i], xv = bx[i];
                int jn = j + PFD;
                if (jn < CLEN) {
                    bd[i] = (float)deltah[base + (size_t)jn * D_INNER];
                    bx[i] = (float)xch[base + (size_t)jn * D_INNER];
                }
                S += dv;
                float dbx = dv * xv;
                float rp[16];
                pow_tree(__expf(dv * An0), rp);
                #pragma unroll
                for (int n = 0; n < 16; ++n)
                    h[n] = rp[n] * h[n] + dbx * sB[j][n];
            }
        }
    } else {
        for (int jb = 0; jb < CLEN; jb += PFD) {
            #pragma unroll
            for (int i = 0; i < PFD; ++i) {
                int j = jb + i;
                float dv = bd[i], xv = bx[i];
                int jn = j + PFD;
                if (jn < CLEN) {
                    bd[i] = (float)deltah[base + (size_t)jn * D_INNER];
                    bx[i] = (float)xch[base + (size_t)jn * D_INNER];
                }
                S += dv;
                float dbx = dv * xv;
                #pragma unroll
                for (int n = 0; n < 16; ++n)
                    h[n] = __expf(dv * An[n]) * h[n] + dbx * sB[j][n];
            }
        }
    }

    size_t o = ((size_t)(b * NCH + c) * D_INNER + d) * 16;
    float4* hp = (float4*)(hlocal + o);
    #pragma unroll
    for (int q = 0; q < 4; ++q)
        hp[q] = make_float4(h[q * 4], h[q * 4 + 1], h[q * 4 + 2], h[q * 4 + 3]);
    Ssum[(size_t)(b * NCH + c) * D_INNER + d] = S;
}

// ---------------------------------------------------------------------------
// Scan pass 2 (R10: combine FUSED IN): each block computes its own exclusive
// chunk-prefix h0 directly from hlocal/Ssum -- the identical recurrence
// combine used (H = exp(An*S)*H + hl, chunks ascending => bit-identical),
// pow_tree on the fast path (1 exp + tree instead of 16 exp per chunk).
// Eliminates the scan_combine kernel and the 32MB h0buf round-trip.
// Then replay from h0; y = sum_n h*C; fuse +xc*D and *pre-silu'd gate.
// ---------------------------------------------------------------------------
__global__ __launch_bounds__(256) void scan_part2(const _Float16* __restrict__ deltah,
                                                  const _Float16* __restrict__ xch,
                                                  const float* __restrict__ Bm,
                                                  const float* __restrict__ Cm,
                                                  const float* __restrict__ hlocal,
                                                  const float* __restrict__ Ssum,
                                                  const float* __restrict__ A_log,
                                                  const float* __restrict__ Dp,
                                                  const _Float16* __restrict__ sresh,
                                                  _Float16* __restrict__ yhalf) {
    const int t = threadIdx.x;
    const int d = blockIdx.x * 256 + t;
    const int c = blockIdx.y;
    const int b = blockIdx.z;

    float An[16];
    {
        const float4* ap = (const float4*)(A_log + (size_t)d * 16);
        #pragma unroll
        for (int q = 0; q < 4; ++q) {
            float4 v = ap[q];
            An[q * 4 + 0] = -__expf(v.x); An[q * 4 + 1] = -__expf(v.y);
            An[q * 4 + 2] = -__expf(v.z); An[q * 4 + 3] = -__expf(v.w);
        }
    }
    const float An0 = An[0];
    bool fast = An0 < 0.f;
    #pragma unroll
    for (int n = 0; n < 16; ++n)
        fast = fast && (fabsf(An[n] - (float)(n + 1) * An0) < 1e-3f * fabsf(An[n]));

    __shared__ float sB[CLEN][16];
    __shared__ float sC[CLEN][16];
    {
        size_t l0 = (size_t)(b * L_SEQ + c * CLEN) * 16;
        #pragma unroll
        for (int i = 0; i < (CLEN * 16) / 256; ++i) {
            int idx = t + i * 256;
            sB[idx >> 4][idx & 15] = Bm[l0 + idx];
            sC[idx >> 4][idx & 15] = Cm[l0 + idx];
        }
    }
    __syncthreads();

    // ---- exclusive chunk-prefix (replaces combine + h0buf) ----
    float h[16];
    #pragma unroll
    for (int n = 0; n < 16; ++n) h[n] = 0.f;
    {
        const float*  Sp = Ssum   + (size_t)b * NCH * D_INNER + d;
        const float4* Hp = (const float4*)(hlocal
                           + ((size_t)b * NCH * D_INNER + d) * 16);
        const size_t hstep = (size_t)D_INNER * 4;   // float4 stride per chunk
        if (fast) {
            #pragma unroll 2
            for (int cc = 0; cc < c; ++cc) {
                float S = Sp[(size_t)cc * D_INNER];
                const float4* hp = Hp + (size_t)cc * hstep;
                float4 v0 = hp[0], v1 = hp[1], v2 = hp[2], v3 = hp[3];
                float rp[16];
                pow_tree(__expf(S * An0), rp);
                h[0]  = rp[0]  * h[0]  + v0.x; h[1]  = rp[1]  * h[1]  + v0.y;
                h[2]  = rp[2]  * h[2]  + v0.z; h[3]  = rp[3]  * h[3]  + v0.w;
                h[4]  = rp[4]  * h[4]  + v1.x; h[5]  = rp[5]  * h[5]  + v1.y;
                h[6]  = rp[6]  * h[6]  + v1.z; h[7]  = rp[7]  * h[7]  + v1.w;
                h[8]  = rp[8]  * h[8]  + v2.x; h[9]  = rp[9]  * h[9]  + v2.y;
                h[10] = rp[10] * h[10] + v2.z; h[11] = rp[11] * h[11] + v2.w;
                h[12] = rp[12] * h[12] + v3.x; h[13] = rp[13] * h[13] + v3.y;
                h[14] = rp[14] * h[14] + v3.z; h[15] = rp[15] * h[15] + v3.w;
            }
        } else {
            for (int cc = 0; cc < c; ++cc) {
                float S = Sp[(size_t)cc * D_INNER];
                const float* hl = (const float*)(Hp + (size_t)cc * hstep);
                #pragma unroll
                for (int n = 0; n < 16; ++n)
                    h[n] = __expf(An[n] * S) * h[n] + hl[n];
            }
        }
    }
    const float Dv = Dp[d];

    size_t base = (size_t)(b * L_SEQ + c * CLEN) * D_INNER + d;
    float bd[PFD], bx[PFD], bg[PFD];
    #pragma unroll
    for (int i = 0; i < PFD; ++i) {
        bd[i] = (float)deltah[base + (size_t)i * D_INNER];
        bx[i] = (float)xch[base + (size_t)i * D_INNER];
        bg[i] = (float)sresh[base + (size_t)i * D_INNER];
    }

    if (fast) {
        for (int jb = 0; jb < CLEN; jb += PFD) {
            #pragma unroll
            for (int i = 0; i < PFD; ++i) {
                int j = jb + i;
                float dv = bd[i], xv = bx[i], gv = bg[i];
                int jn = j + PFD;
                if (jn < CLEN) {
                    bd[i] = (float)deltah[base + (size_t)jn * D_INNER];
                    bx[i] = (float)xch[base + (size_t)jn * D_INNER];
                    bg[i] = (float)sresh[base + (size_t)jn * D_INNER];
                }
                float dbx = dv * xv;
                float rp[16];
                pow_tree(__expf(dv * An0), rp);
                float y0 = 0.f, y1 = 0.f, y2 = 0.f, y3 = 0.f;
                #pragma unroll
                for (int n = 0; n < 16; n += 4) {
                    h[n]     = rp[n]     * h[n]     + dbx * sB[j][n];
                    h[n + 1] = rp[n + 1] * h[n + 1] + dbx * sB[j][n + 1];
                    h[n + 2] = rp[n + 2] * h[n + 2] + dbx * sB[j][n + 2];
                    h[n + 3] = rp[n + 3] * h[n + 3] + dbx * sB[j][n + 3];
                    y0 += h[n]     * sC[j][n];
                    y1 += h[n + 1] * sC[j][n + 1];
                    y2 += h[n + 2] * sC[j][n + 2];
                    y3 += h[n + 3] * sC[j][n + 3];
                }
                float y = (y0 + y1) + (y2 + y3);
                float yv = (y + xv * Dv) * gv;
                yhalf[base + (size_t)j * D_INNER] = (_Float16)yv;
            }
        }
    } else {
        for (int jb = 0; jb < CLEN; jb += PFD) {
            #pragma unroll
            for (int i = 0; i < PFD; ++i) {
                int j = jb + i;
                float dv = bd[i], xv = bx[i], gv = bg[i];
                int jn = j + PFD;
                if (jn < CLEN) {
                    bd[i] = (float)deltah[base + (size_t)jn * D_INNER];
                    bx[i] = (float)xch[base + (size_t)jn * D_INNER];
                    bg[i] = (float)sresh[base + (size_t)jn * D_INNER];
                }
                float dbx = dv * xv;
                float y = 0.f;
                #pragma unroll
                for (int n = 0; n < 16; ++n) {
                    h[n] = __expf(dv * An[n]) * h[n] + dbx * sB[j][n];
                    y += h[n] * sC[j][n];
                }
                float yv = (y + xv * Dv) * gv;
                yhalf[base + (size_t)j * D_INNER] = (_Float16)yv;
            }
        }
    }
}

extern "C" void kernel_launch(void* const* d_in, const int* in_sizes, int n_in,
                              void* d_out, int out_size, void* d_ws, size_t ws_size,
                              hipStream_t stream) {
    const float* x      = (const float*)d_in[0];
    const float* W_in   = (const float*)d_in[1];
    const float* conv_w = (const float*)d_in[2];
    const float* conv_b = (const float*)d_in[3];
    const float* W_x    = (const float*)d_in[4];
    const float* W_dt   = (const float*)d_in[5];
    const float* b_dt   = (const float*)d_in[6];
    const float* A_log  = (const float*)d_in[7];
    const float* D_par  = (const float*)d_in[8];
    const float* W_out  = (const float*)d_in[9];
    float* out = (float*)d_out;

    char* wsb = (char*)d_ws;
    _Float16*  xsh    = (_Float16*)(wsb + 0);             // 16,777,216 B
    _Float16*  sresh  = (_Float16*)(wsb + 16777216);      // 16,777,216 B
    _Float16*  deltah = (_Float16*)(wsb + 33554432);      // 16,777,216 B
    _Float16*  xch    = (_Float16*)(wsb + 50331648);      // 16,777,216 B
    _Float16*  xf16   = (_Float16*)(wsb + 67108864);      //  8,388,608 B (dead after K1)
    _Float16*  WinT   = (_Float16*)(wsb + 75497472);      //  8,388,608 B (dead after K1)
    _Float16*  yhalf  = (_Float16*)(wsb + 67108864);      // 16,777,216 B (aliases xf16+WinT)
    _Float16*  WxT    = (_Float16*)(wsb + 83886080);      //    393,216 B
    _Float16*  WdtT   = (_Float16*)(wsb + 84279296);      //    262,144 B
    // (xdh slot unused -- delta fused; h0buf slot unused -- combine fused)
    float*     Bbuf   = (float*)(wsb + 85065728);         //    262,144 B
    float*     Cbuf   = (float*)(wsb + 85327872);         //    262,144 B
    float*     Ssum   = (float*)(wsb + 85590016);         //  1,048,576 B
    float*     hloc   = (float*)(wsb + 86638592);         // 16,777,216 B
    _Float16*  WoutT  = (_Float16*)(wsb + 120193024);     //  4,194,304 B
    float*     cwT    = (float*)(wsb + 124387328);        //     32,768 B
    // end: 124,420,096 B

    dim3 blk(256);

    // 1. fused prep: all weight transposes + x cast + conv_w transpose
    prep<<<dim3(10561), blk, 0, stream>>>(x, xf16, W_in, WinT, W_x, WxT,
                                          W_dt, WdtT, W_out, WoutT, conv_w, cwT);
    // 2. K1: [xs fp16 | silu(res) fp16] = x @ W_in  (M=4096, N=4096, K=1024)
    gemm_k1<<<dim3(16, 16), dim3(512), 0, stream>>>(xf16, WinT, xsh, sresh);
    // 3. conv + SiLU -> xch fp16  (coalesced cwT weights)
    conv_silu<<<dim3((size_t)MM * D_INNER / 8 / 256), blk, 0, stream>>>(xsh, cwT, conv_b, xch);
    // 4. fused xd + delta: Bm/Cm fp32 + deltah fp16
    gemm_xd_delta<<<dim3(MM / 16), blk, 0, stream>>>(xch, WxT, WdtT, b_dt, Bbuf, Cbuf, deltah);
    // 5. scan pass 1  (NCH=64, CLEN=32)
    scan_part1<<<dim3(D_INNER / 256, NCH, B_SZ), blk, 0, stream>>>(deltah, xch, Bbuf, A_log, hloc, Ssum);
    // 6. scan pass 2 with fused chunk-prefix (+gating) -> yhalf fp16
    scan_part2<<<dim3(D_INNER / 256, NCH, B_SZ), blk, 0, stream>>>(deltah, xch, Bbuf, Cbuf, hloc, Ssum, A_log, D_par, sresh, yhalf);
    // 7. K5: out = y @ W_out  (M=4096, N=1024, K=2048)
    gemm_f16<0><<<dim3(8, 32), blk, 0, stream>>>(
        yhalf, WoutT, nullptr, out, nullptr, nullptr, MM, D_MODEL, D_INNER, D_MODEL);
}

// Round 12
// 317.759 us; speedup vs baseline: 1.0926x; 1.0926x over previous
//
#include <hip/hip_runtime.h>
#include <math.h>

#define B_SZ    2
#define L_SEQ   2048
#define D_MODEL 1024
#define D_INNER 2048
#define D_STATE 16
#define DT_RANK 64
#define MM      (B_SZ * L_SEQ)   // 4096 rows
#define NCH     64               // scan chunks (R8-proven: scan is latency-bound, needs TLP)
#define CLEN    (L_SEQ / NCH)    // 32 steps per chunk
#define PFD     8                // scan prefetch depth

typedef _Float16 h8v __attribute__((ext_vector_type(8)));
typedef _Float16 h4v __attribute__((ext_vector_type(4)));
typedef float f32x4 __attribute__((ext_vector_type(4)));

// Async global->LDS DMA, 16B per lane. LDS dest = uniform base + lane*16.
__device__ __forceinline__ void gload16(const void* g, void* l) {
    __builtin_amdgcn_global_load_lds((const __attribute__((address_space(1))) void*)g,
                                     (__attribute__((address_space(3))) void*)l, 16, 0, 0);
}

// r^(1..16) via repeated-squaring tree: depth <=4 (vs 16-deep serial fold).
__device__ __forceinline__ void pow_tree(float r1, float* rp) {
    float r2 = r1 * r1, r3 = r2 * r1, r4 = r2 * r2;
    float r8 = r4 * r4;
    rp[0] = r1;      rp[1] = r2;      rp[2] = r3;      rp[3] = r4;
    rp[4] = r4 * r1; rp[5] = r4 * r2; rp[6] = r4 * r3; rp[7] = r8;
    rp[8] = r8 * r1; rp[9] = r8 * r2; rp[10] = r8 * r3; rp[11] = r8 * r4;
    rp[12] = r8 * rp[4]; rp[13] = r8 * rp[5]; rp[14] = r8 * rp[6]; rp[15] = r8 * r8;
}

// ---------------------------------------------------------------------------
// prep: all weight transposes (fp32 -> fp16 T[N][K]) + x -> fp16 cast +
// conv_w transpose to [k][d] fp32.
// ---------------------------------------------------------------------------
__global__ __launch_bounds__(256) void prep(const float* __restrict__ x,
                                            _Float16* __restrict__ xf16,
                                            const float* __restrict__ W_in,
                                            _Float16* __restrict__ WinT,
                                            const float* __restrict__ W_x,
                                            _Float16* __restrict__ WxT,
                                            const float* __restrict__ W_dt,
                                            _Float16* __restrict__ WdtT,
                                            const float* __restrict__ W_out,
                                            _Float16* __restrict__ WoutT,
                                            const float* __restrict__ cw,
                                            float* __restrict__ cwT) {
    __shared__ float t[32][33];
    const int b = blockIdx.x;
    const float* W; _Float16* T; int K, N, tile;
    if (b < 4096)      { W = W_in;  T = WinT;  K = 1024; N = 4096; tile = b; }
    else if (b < 4288) { W = W_x;   T = WxT;   K = 2048; N = 96;   tile = b - 4096; }
    else if (b < 4416) { W = W_dt;  T = WdtT;  K = 64;   N = 2048; tile = b - 4288; }
    else if (b < 6464) { W = W_out; T = WoutT; K = 2048; N = 1024; tile = b - 4416; }
    else if (b < 10560) {
        int idx = (b - 6464) * 256 + threadIdx.x;
        float4 v = ((const float4*)x)[idx];
        h4v h = {(_Float16)v.x, (_Float16)v.y, (_Float16)v.z, (_Float16)v.w};
        *(h4v*)(xf16 + (size_t)idx * 4) = h;
        return;
    } else {
        // conv_w [2048][4] -> cwT [4][2048]
        for (int i = threadIdx.x; i < D_INNER * 4; i += 256) {
            int d = i >> 2, k = i & 3;
            cwT[k * D_INNER + d] = cw[i];
        }
        return;
    }
    const int ntx = N / 32;
    const int k0 = (tile / ntx) * 32, n0 = (tile % ntx) * 32;
    #pragma unroll
    for (int i = 0; i < 4; ++i) {
        int idx = threadIdx.x + i * 256;
        int r = idx >> 5, c = idx & 31;
        t[r][c] = W[(size_t)(k0 + r) * N + n0 + c];
    }
    __syncthreads();
    #pragma unroll
    for (int i = 0; i < 4; ++i) {
        int idx = threadIdx.x + i * 256;
        int n = idx >> 5, k = idx & 31;
        T[(size_t)(n0 + n) * K + k0 + k] = (_Float16)t[k][n];
    }
}

// ---------------------------------------------------------------------------
// K1 (R1 structure, best measured): 256x256 tile, BK=64, 8 waves (2Mx4N),
// double-buffered 2x64KiB LDS, 4 phases/K-tile x 16 MFMA.
// R1-R4 ledger: K1 family plateaus ~46us (~750 TF); drilling stopped.
// ANCHOR KERNEL: byte-frozen since R5; healthy-node band = 46-49us.
// Epilogue: cols<2048 -> H (xs); cols>=2048 -> silu -> Hg (gate).
// ---------------------------------------------------------------------------
#define LDA_(mi, ks) (*(const h8v*)(smb + cb_ + rowA + (mi) * 2048 + ((ks) ? ps1 : ps0)))
#define LDB_(ni, ks) (*(const h8v*)(smb + cb_ + 32768 + rowB + (ni) * 2048 + ((ks) ? ps1 : ps0)))
#define PH(m0, m1) \
    _Pragma("unroll") \
    for (int ni = 0; ni < 4; ++ni) { \
        acc[m0][ni] = __builtin_amdgcn_mfma_f32_16x16x32_f16(aF0, bF[2 * ni],     acc[m0][ni], 0, 0, 0); \
        acc[m0][ni] = __builtin_amdgcn_mfma_f32_16x16x32_f16(aF1, bF[2 * ni + 1], acc[m0][ni], 0, 0, 0); \
        acc[m1][ni] = __builtin_amdgcn_mfma_f32_16x16x32_f16(aF2, bF[2 * ni],     acc[m1][ni], 0, 0, 0); \
        acc[m1][ni] = __builtin_amdgcn_mfma_f32_16x16x32_f16(aF3, bF[2 * ni + 1], acc[m1][ni], 0, 0, 0); \
    }

__global__ __launch_bounds__(512, 2) void gemm_k1(const _Float16* __restrict__ A,
                                                  const _Float16* __restrict__ Bt,
                                                  _Float16* __restrict__ H,
                                                  _Float16* __restrict__ Hg) {
    // 128 KiB LDS: [A buf0 | B buf0 | A buf1 | B buf1], 32 KiB each.
    __shared__ _Float16 smem[65536];
    char* smb = (char*)smem;

    const int tid  = threadIdx.x;
    const int wave = tid >> 6, lane = tid & 63;
    const int wm = wave >> 2, wn = wave & 3;       // 2 x 4 wave grid
    const int lm = lane & 15, lq = lane >> 4;
    const int bm = blockIdx.y * 256, bn = blockIdx.x * 256;

    // read addressing: 16B k-slot s at physical slot s ^ (row&7); row&7 == lm&7
    const int ps0 = ((lq)     ^ (lm & 7)) << 4;
    const int ps1 = ((lq + 4) ^ (lm & 7)) << 4;
    const int rowA = (wm * 128 + lm) << 7;         // 128 B per row (BK=64 fp16)
    const int rowB = (wn * 64 + lm) << 7;

    // staging: LDS linear (wave*4+q)*1024 + lane*16 -> logical slot = (lane&7)^(lane>>3)
    const int srow  = lane >> 3;
    const int sslot = (lane & 7) ^ srow;
    const _Float16* pA = A  + (size_t)(bm + wave * 32 + srow) * 1024 + sslot * 8;
    const _Float16* pB = Bt + (size_t)(bn + wave * 32 + srow) * 1024 + sslot * 8;
    char* dA = smb + wave * 4096;                  // + buf*65536
    char* dB = smb + 32768 + wave * 4096;

    f32x4 acc[8][4];
    #pragma unroll
    for (int i = 0; i < 8; ++i)
        #pragma unroll
        for (int j = 0; j < 4; ++j) acc[i][j] = (f32x4){0.f, 0.f, 0.f, 0.f};

    // prologue: stage K-tile 0 into buf 0
    #pragma unroll
    for (int q = 0; q < 4; ++q) {
        gload16(pA + q * 8192, dA + q * 1024);
        gload16(pB + q * 8192, dB + q * 1024);
    }
    asm volatile("s_waitcnt vmcnt(0)" ::: "memory");
    __builtin_amdgcn_s_barrier();

    int cb_ = 0;
    for (int t = 0; t < 16; ++t) {
        const int nb_ = 65536 - cb_;
        const bool pf = (t < 15);
        const size_t kn = (size_t)(t + 1) * 64;    // next K-tile element offset

        h8v aF0, aF1, aF2, aF3;
        h8v bF[8];

        // ---- phase 1: mi 0,1 | read all 8 B-frags | stage next A-tile ----
        aF0 = LDA_(0, 0); aF1 = LDA_(0, 1); aF2 = LDA_(1, 0); aF3 = LDA_(1, 1);
        #pragma unroll
        for (int ni = 0; ni < 4; ++ni) { bF[2 * ni] = LDB_(ni, 0); bF[2 * ni + 1] = LDB_(ni, 1); }
        if (pf) {
            #pragma unroll
            for (int q = 0; q < 4; ++q) gload16(pA + kn + q * 8192, dA + nb_ + q * 1024);
        }
        __builtin_amdgcn_s_barrier();
        asm volatile("s_waitcnt lgkmcnt(0)" ::: "memory");
        __builtin_amdgcn_s_setprio(1);
        PH(0, 1);
        __builtin_amdgcn_s_setprio(0);
        __builtin_amdgcn_s_barrier();

        // ---- phase 2: mi 2,3 | stage next B-tile ----
        aF0 = LDA_(2, 0); aF1 = LDA_(2, 1); aF2 = LDA_(3, 0); aF3 = LDA_(3, 1);
        if (pf) {
            #pragma unroll
            for (int q = 0; q < 4; ++q) gload16(pB + kn + q * 8192, dB + nb_ + q * 1024);
        }
        __builtin_amdgcn_s_barrier();
        asm volatile("s_waitcnt lgkmcnt(0)" ::: "memory");
        __builtin_amdgcn_s_setprio(1);
        PH(2, 3);
        __builtin_amdgcn_s_setprio(0);
        __builtin_amdgcn_s_barrier();

        // ---- phase 3: mi 4,5 ----
        aF0 = LDA_(4, 0); aF1 = LDA_(4, 1); aF2 = LDA_(5, 0); aF3 = LDA_(5, 1);
        __builtin_amdgcn_s_barrier();
        asm volatile("s_waitcnt lgkmcnt(0)" ::: "memory");
        __builtin_amdgcn_s_setprio(1);
        PH(4, 5);
        __builtin_amdgcn_s_setprio(0);
        __builtin_amdgcn_s_barrier();

        // ---- phase 4: mi 6,7 | counted A'-wait pre-bar, B' drain post-MFMA ----
        aF0 = LDA_(6, 0); aF1 = LDA_(6, 1); aF2 = LDA_(7, 0); aF3 = LDA_(7, 1);
        asm volatile("s_waitcnt vmcnt(4)" ::: "memory");   // A' (issued P1) done
        __builtin_amdgcn_s_barrier();
        asm volatile("s_waitcnt lgkmcnt(0)" ::: "memory");
        __builtin_amdgcn_s_setprio(1);
        PH(6, 7);
        __builtin_amdgcn_s_setprio(0);
        asm volatile("s_waitcnt vmcnt(0)" ::: "memory");   // B' (issued P2) done
        __builtin_amdgcn_s_barrier();                      // -> next tile visible

        cb_ = nb_;
    }

    // epilogue: staging LDS is free; per-wave 16x72 fp16 transpose chunks
    _Float16* ep = smem + wave * 2048;
    const bool gate = (bn >= 2048);
    _Float16* dst = gate ? Hg : H;
    const int cbase = bn + wn * 64 - (gate ? 2048 : 0);
    #pragma unroll
    for (int mi = 0; mi < 8; ++mi) {
        #pragma unroll
        for (int ni = 0; ni < 4; ++ni)
            #pragma unroll
            for (int r = 0; r < 4; ++r) {
                float v = acc[mi][ni][r];
                if (gate) v = v / (1.f + __expf(-v));
                ep[(lq * 4 + r) * 72 + ni * 16 + lm] = (_Float16)v;
            }
        int rowb = bm + wm * 128 + mi * 16;
        #pragma unroll
        for (int i = 0; i < 2; ++i) {
            int ch = lane + 64 * i;
            int row = ch >> 3, c8 = (ch & 7) * 8;
            *(h8v*)&dst[(size_t)(rowb + row) * 2048 + cbase + c8] =
                *(const h8v*)&ep[row * 72 + c8];
        }
    }
}
#undef LDA_
#undef LDB_
#undef PH

// ---------------------------------------------------------------------------
// fp16 MFMA GEMM, double-buffered async DMA: C = A[M][K] @ Bt[N][K]^T.
// 128x128 tile, 256 thr, 4 waves 2x2, wave 64x64 (4x4 16x16x32 frags), BK=32.
// (retained for K5)
// EPI 0: fp32 C.
// ---------------------------------------------------------------------------
template<int EPI>
__global__ __launch_bounds__(256) void gemm_f16(const _Float16* __restrict__ A,
                                                const _Float16* __restrict__ Bt,
                                                const float* __restrict__ bias,
                                                float* __restrict__ C,
                                                _Float16* __restrict__ H,
                                                _Float16* __restrict__ Hg,
                                                int M, int N, int K, int ldc) {
    __shared__ _Float16 smemh[16384];   // 32KB: staging dbuf, reused by epilogue

    const int tid = threadIdx.x;
    const int wave = tid >> 6, lane = tid & 63;
    const int bm = blockIdx.y * 128, bn = blockIdx.x * 128;

    const int lrow = lane >> 2, pc = lane & 3;
    const int ar = wave * 32 + lrow;
    const size_t gA = (size_t)(bm + ar) * K + ((pc ^ ((ar >> 1) & 3)) * 8);
    const size_t gB = (size_t)(bn + ar) * K + ((pc ^ ((ar >> 1) & 3)) * 8);
    const int lofs = (wave * 32) * 32;

    const int lm = lane & 15, lq = lane >> 4;
    const int rofs = (lq ^ ((lm >> 1) & 3)) * 8;
    const int wm = (wave >> 1) * 64, wn = (wave & 1) * 64;

    f32x4 acc[4][4];
    #pragma unroll
    for (int i = 0; i < 4; ++i)
        #pragma unroll
        for (int j = 0; j < 4; ++j) acc[i][j] = (f32x4){0.f, 0.f, 0.f, 0.f};

    // prologue: fill buffer 0  (A buf at kb*4096, B buf at 8192 + kb*4096)
    gload16(A + gA, smemh + lofs);
    gload16(A + gA + (size_t)16 * K, smemh + lofs + 16 * 32);
    gload16(Bt + gB, smemh + 8192 + lofs);
    gload16(Bt + gB + (size_t)16 * K, smemh + 8192 + lofs + 16 * 32);
    __syncthreads();

    int kb = 0;
    for (int k0 = 0; k0 < K; k0 += 32, kb ^= 1) {
        if (k0 + 32 < K) {   // issue next tile BEFORE computing this one
            int nb = kb ^ 1;
            gload16(A + gA + k0 + 32, smemh + nb * 4096 + lofs);
            gload16(A + gA + k0 + 32 + (size_t)16 * K, smemh + nb * 4096 + lofs + 16 * 32);
            gload16(Bt + gB + k0 + 32, smemh + 8192 + nb * 4096 + lofs);
            gload16(Bt + gB + k0 + 32 + (size_t)16 * K, smemh + 8192 + nb * 4096 + lofs + 16 * 32);
        }

        const _Float16* sA = smemh + kb * 4096;
        const _Float16* sB = smemh + 8192 + kb * 4096;
        h8v fa[4], fb[4];
        #pragma unroll
        for (int i = 0; i < 4; ++i) {
            fa[i] = *(const h8v*)&sA[(wm + i * 16 + lm) * 32 + rofs];
            fb[i] = *(const h8v*)&sB[(wn + i * 16 + lm) * 32 + rofs];
        }
        #pragma unroll
        for (int mi = 0; mi < 4; ++mi)
            #pragma unroll
            for (int ni = 0; ni < 4; ++ni)
                acc[mi][ni] = __builtin_amdgcn_mfma_f32_16x16x32_f16(fa[mi], fb[ni], acc[mi][ni], 0, 0, 0);
        __syncthreads();   // drains next-tile DMA; protects buffer reuse
    }
    // after final barrier all waves are done with staging LDS -> reuse it.

    if (EPI == 0) {
        float* ep = (float*)smemh + wave * 1088;   // 16 x 68 fp32 (padded)
        #pragma unroll
        for (int mi = 0; mi < 4; ++mi) {
            #pragma unroll
            for (int ni = 0; ni < 4; ++ni)
                #pragma unroll
                for (int r = 0; r < 4; ++r)
                    ep[(lq * 4 + r) * 68 + ni * 16 + lm] = acc[mi][ni][r];
            int rowb = bm + wm + mi * 16;
            #pragma unroll
            for (int i = 0; i < 4; ++i) {
                int ch = lane + 64 * i;
                int row = ch >> 4, c4 = (ch & 15) * 4;
                *(float4*)&C[(size_t)(rowb + row) * ldc + bn + wn + c4] =
                    *(const float4*)&ep[row * 68 + c4];
            }
        }
    } else {
        _Float16* ep = smemh + wave * 1152;        // 16 x 72 fp16 (padded, 16B rows)
        const bool gate = (EPI == 2) && (bn >= 2048);
        _Float16* dst = gate ? Hg : H;
        const int cb = bn + wn - (gate ? 2048 : 0);
        #pragma unroll
        for (int mi = 0; mi < 4; ++mi) {
            #pragma unroll
            for (int ni = 0; ni < 4; ++ni) {
                int col = bn + wn + ni * 16 + lm;
                #pragma unroll
                for (int r = 0; r < 4; ++r) {
                    float v = acc[mi][ni][r];
                    if (EPI == 1) {
                        float a = v + bias[col];
                        v = (a > 20.f) ? a : __logf(1.f + __expf(a));
                    } else if (gate) {
                        v = v / (1.f + __expf(-v));
                    }
                    ep[(lq * 4 + r) * 72 + ni * 16 + lm] = (_Float16)v;
                }
            }
            int rowb = bm + wm + mi * 16;
            #pragma unroll
            for (int i = 0; i < 2; ++i) {
                int ch = lane + 64 * i;
                int row = ch >> 3, c8 = (ch & 7) * 8;
                *(h8v*)&dst[(size_t)(rowb + row) * ldc + cb + c8] =
                    *(const h8v*)&ep[row * 72 + c8];
            }
        }
    }
}

// ---------------------------------------------------------------------------
// Fused xd + delta kernel (R9): per block (16 rows, 256 blocks):
//   phase 1: xd[16][96] = xch_rows @ WxT^T (4-wave K-split, LDS reduction);
//   phase 2: delta[16][2048] = softplus(xd @ WdtT^T + b_dt) (4-wave N-split).
// ---------------------------------------------------------------------------
__global__ __launch_bounds__(256) void gemm_xd_delta(const _Float16* __restrict__ xch,
                                                     const _Float16* __restrict__ WxT,
                                                     const _Float16* __restrict__ WdtT,
                                                     const float* __restrict__ b_dt,
                                                     float* __restrict__ Bm,
                                                     float* __restrict__ Cm,
                                                     _Float16* __restrict__ deltah) {
    __shared__ float sred[3][64][25];       // waves 1..3 partials (6 frags x 4), +1 pad
    __shared__ _Float16 xd16[16 * 72];      // xd rows (padded: 144B rows, 16B-aligned)
    __shared__ _Float16 epd[4][16 * 72];    // per-wave delta transpose staging
    const int tid = threadIdx.x;
    const int wave = tid >> 6, lane = tid & 63;
    const int lm = lane & 15, lq = lane >> 4;
    const int m0 = blockIdx.x * 16;

    // ---------------- phase 1: xd (K-split) ----------------
    const int kbase = wave * 512;
    const _Float16* pa = xch + (size_t)(m0 + lm) * D_INNER + kbase + lq * 8;
    const _Float16* pb = WxT + (size_t)lm * D_INNER + kbase + lq * 8;

    f32x4 acc[6];
    #pragma unroll
    for (int i = 0; i < 6; ++i) acc[i] = (f32x4){0.f, 0.f, 0.f, 0.f};

    #pragma unroll 2
    for (int it = 0; it < 16; ++it) {
        const int ko = it * 32;
        h8v fa = *(const h8v*)(pa + ko);
        #pragma unroll
        for (int nf = 0; nf < 6; ++nf) {
            h8v fb = *(const h8v*)(pb + (size_t)nf * 16 * D_INNER + ko);
            acc[nf] = __builtin_amdgcn_mfma_f32_16x16x32_f16(fa, fb, acc[nf], 0, 0, 0);
        }
    }

    if (wave != 0) {
        #pragma unroll
        for (int nf = 0; nf < 6; ++nf)
            #pragma unroll
            for (int r = 0; r < 4; ++r)
                sred[wave - 1][lane][nf * 4 + r] = acc[nf][r];
    }
    __syncthreads();
    if (wave == 0) {
        #pragma unroll
        for (int nf = 0; nf < 6; ++nf) {
            int col = nf * 16 + lm;
            #pragma unroll
            for (int r = 0; r < 4; ++r) {
                float v = ((acc[nf][r] + sred[0][lane][nf * 4 + r])
                           + sred[1][lane][nf * 4 + r]) + sred[2][lane][nf * 4 + r];
                int row = lq * 4 + r;               // block-local row
                if (nf < 4)        xd16[row * 72 + col] = (_Float16)v;
                else if (col < 80) Bm[(size_t)(m0 + row) * 16 + (col - 64)] = v;
                else               Cm[(size_t)(m0 + row) * 16 + (col - 80)] = v;
            }
        }
    }
    __syncthreads();

    // ---------------- phase 2: delta (N-split) ----------------
    h8v fa0 = *(const h8v*)&xd16[lm * 72 + lq * 8];        // k 0..31
    h8v fa1 = *(const h8v*)&xd16[lm * 72 + 32 + lq * 8];   // k 32..63
    const int nbase = wave * 512;
    _Float16* ep = epd[wave];

    #pragma unroll 1
    for (int g = 0; g < 8; ++g) {          // groups of 4 n-tiles (64 cols)
        #pragma unroll
        for (int t = 0; t < 4; ++t) {
            const int col = nbase + g * 64 + t * 16 + lm;
            const _Float16* wrow = WdtT + (size_t)col * 64;
            h8v fb0 = *(const h8v*)(wrow + lq * 8);
            h8v fb1 = *(const h8v*)(wrow + 32 + lq * 8);
            f32x4 a = __builtin_amdgcn_mfma_f32_16x16x32_f16(fa0, fb0,
                        (f32x4){0.f, 0.f, 0.f, 0.f}, 0, 0, 0);
            a = __builtin_amdgcn_mfma_f32_16x16x32_f16(fa1, fb1, a, 0, 0, 0);
            const float bv = b_dt[col];
            #pragma unroll
            for (int r = 0; r < 4; ++r) {
                float v = a[r] + bv;
                v = (v > 20.f) ? v : __logf(1.f + __expf(v));
                ep[(lq * 4 + r) * 72 + t * 16 + lm] = (_Float16)v;
            }
        }
        // wave-synchronous LDS transpose -> 16B stores
        #pragma unroll
        for (int i = 0; i < 2; ++i) {
            int ch = lane + 64 * i;
            int row = ch >> 3, c8 = (ch & 7) * 8;
            *(h8v*)&deltah[(size_t)(m0 + row) * D_INNER + nbase + g * 64 + c8] =
                *(const h8v*)&ep[row * 72 + c8];
        }
    }
}

// ---------------------------------------------------------------------------
// Depthwise causal conv (k=4) + bias + SiLU, 8 elements/thread.
// ---------------------------------------------------------------------------
__global__ __launch_bounds__(256) void conv_silu(const _Float16* __restrict__ xsh,
                                                 const float* __restrict__ cwT,
                                                 const float* __restrict__ cb,
                                                 _Float16* __restrict__ xch) {
    int idx = blockIdx.x * 256 + threadIdx.x;
    int d0 = (idx * 8) & (D_INNER - 1);
    int m  = (idx * 8) >> 11;
    int l  = m & (L_SEQ - 1);
    float acc[8];
    {
        float4 c0 = *(const float4*)&cb[d0];
        float4 c1 = *(const float4*)&cb[d0 + 4];
        acc[0] = c0.x; acc[1] = c0.y; acc[2] = c0.z; acc[3] = c0.w;
        acc[4] = c1.x; acc[5] = c1.y; acc[6] = c1.z; acc[7] = c1.w;
    }
    #pragma unroll
    for (int k = 0; k < 4; ++k) {
        int ll = l - 3 + k;
        if (ll >= 0) {
            h8v v = *(const h8v*)(xsh + (size_t)(m - 3 + k) * D_INNER + d0);
            float4 w0 = *(const float4*)&cwT[k * D_INNER + d0];
            float4 w1 = *(const float4*)&cwT[k * D_INNER + d0 + 4];
            acc[0] += (float)v[0] * w0.x; acc[1] += (float)v[1] * w0.y;
            acc[2] += (float)v[2] * w0.z; acc[3] += (float)v[3] * w0.w;
            acc[4] += (float)v[4] * w1.x; acc[5] += (float)v[5] * w1.y;
            acc[6] += (float)v[6] * w1.z; acc[7] += (float)v[7] * w1.w;
        }
    }
    h8v o;
    #pragma unroll
    for (int j = 0; j < 8; ++j) {
        float s = acc[j] / (1.f + __expf(-acc[j]));
        o[j] = (_Float16)s;
    }
    *(h8v*)(xch + (size_t)idx * 8) = o;
}

// ---------------------------------------------------------------------------
// Scan pass 1: per (b, chunk, d) chunk-local final state (h0=0) + S=sum(delta).
// Fast path uses pow_tree (R8).
// ---------------------------------------------------------------------------
__global__ __launch_bounds__(256) void scan_part1(const _Float16* __restrict__ deltah,
                                                  const _Float16* __restrict__ xch,
                                                  const float* __restrict__ Bm,
                                                  const float* __restrict__ A_log,
                                                  float* __restrict__ hlocal,
                                                  float* __restrict__ Ssum) {
    const int t = threadIdx.x;
    const int d = blockIdx.x * 256 + t;
    const int c = blockIdx.y;
    const int b = blockIdx.z;

    float An[16];
    {
        const float4* ap = (const float4*)(A_log + (size_t)d * 16);
        #pragma unroll
        for (int q = 0; q < 4; ++q) {
            float4 v = ap[q];
            An[q * 4 + 0] = -__expf(v.x); An[q * 4 + 1] = -__expf(v.y);
            An[q * 4 + 2] = -__expf(v.z); An[q * 4 + 3] = -__expf(v.w);
        }
    }
    const float An0 = An[0];
    bool fast = An0 < 0.f;
    #pragma unroll
    for (int n = 0; n < 16; ++n)
        fast = fast && (fabsf(An[n] - (float)(n + 1) * An0) < 1e-3f * fabsf(An[n]));

    __shared__ float sB[CLEN][16];
    {
        size_t l0 = (size_t)(b * L_SEQ + c * CLEN) * 16;
        #pragma unroll
        for (int i = 0; i < (CLEN * 16) / 256; ++i) {
            int idx = t + i * 256;
            sB[idx >> 4][idx & 15] = Bm[l0 + idx];
        }
    }
    __syncthreads();

    float h[16];
    #pragma unroll
    for (int n = 0; n < 16; ++n) h[n] = 0.f;
    float S = 0.f;

    size_t base = (size_t)(b * L_SEQ + c * CLEN) * D_INNER + d;
    float bd[PFD], bx[PFD];
    #pragma unroll
    for (int i = 0; i < PFD; ++i) {
        bd[i] = (float)deltah[base + (size_t)i * D_INNER];
        bx[i] = (float)xch[base + (size_t)i * D_INNER];
    }

    if (fast) {
        for (int jb = 0; jb < CLEN; jb += PFD) {
            #pragma unroll
            for (int i = 0; i < PFD; ++i) {
                int j = jb + i;
                float dv = bd[i], xv = bx[i];
                int jn = j + PFD;
                if (jn < CLEN) {
                    bd[i] = (float)deltah[base + (size_t)jn * D_INNER];
                    bx[i] = (float)xch[base + (size_t)jn * D_INNER];
                }
                S += dv;
                float dbx = dv * xv;
                float rp[16];
                pow_tree(__expf(dv * An0), rp);
                #pragma unroll
                for (int n = 0; n < 16; ++n)
                    h[n] = rp[n] * h[n] + dbx * sB[j][n];
            }
        }
    } else {
        for (int jb = 0; jb < CLEN; jb += PFD) {
            #pragma unroll
            for (int i = 0; i < PFD; ++i) {
                int j = jb + i;
                float dv = bd[i], xv = bx[i];
                int jn = j + PFD;
                if (jn < CLEN) {
                    bd[i] = (float)deltah[base + (size_t)jn * D_INNER];
                    bx[i] = (float)xch[base + (size_t)jn * D_INNER];
                }
                S += dv;
                float dbx = dv * xv;
                #pragma unroll
                for (int n = 0; n < 16; ++n)
                    h[n] = __expf(dv * An[n]) * h[n] + dbx * sB[j][n];
            }
        }
    }

    size_t o = ((size_t)(b * NCH + c) * D_INNER + d) * 16;
    float4* hp = (float4*)(hlocal + o);
    #pragma unroll
    for (int q = 0; q < 4; ++q)
        hp[q] = make_float4(h[q * 4], h[q * 4 + 1], h[q * 4 + 2], h[q * 4 + 3]);
    Ssum[(size_t)(b * NCH + c) * D_INNER + d] = S;
}

// ---------------------------------------------------------------------------
// Scan pass 2 (combine fused in): each block computes its own exclusive
// chunk-prefix h0 directly from hlocal/Ssum (identical recurrence & order as
// the old combine kernel => bit-identical); then replay + gating.
// ---------------------------------------------------------------------------
__global__ __launch_bounds__(256) void scan_part2(const _Float16* __restrict__ deltah,
                                                  const _Float16* __restrict__ xch,
                                                  const float* __restrict__ Bm,
                                                  const float* __restrict__ Cm,
                                                  const float* __restrict__ hlocal,
                                                  const float* __restrict__ Ssum,
                                                  const float* __restrict__ A_log,
                                                  const float* __restrict__ Dp,
                                                  const _Float16* __restrict__ sresh,
                                                  _Float16* __restrict__ yhalf) {
    const int t = threadIdx.x;
    const int d = blockIdx.x * 256 + t;
    const int c = blockIdx.y;
    const int b = blockIdx.z;

    float An[16];
    {
        const float4* ap = (const float4*)(A_log + (size_t)d * 16);
        #pragma unroll
        for (int q = 0; q < 4; ++q) {
            float4 v = ap[q];
            An[q * 4 + 0] = -__expf(v.x); An[q * 4 + 1] = -__expf(v.y);
            An[q * 4 + 2] = -__expf(v.z); An[q * 4 + 3] = -__expf(v.w);
        }
    }
    const float An0 = An[0];
    bool fast = An0 < 0.f;
    #pragma unroll
    for (int n = 0; n < 16; ++n)
        fast = fast && (fabsf(An[n] - (float)(n + 1) * An0) < 1e-3f * fabsf(An[n]));

    __shared__ float sB[CLEN][16];
    __shared__ float sC[CLEN][16];
    {
        size_t l0 = (size_t)(b * L_SEQ + c * CLEN) * 16;
        #pragma unroll
        for (int i = 0; i < (CLEN * 16) / 256; ++i) {
            int idx = t + i * 256;
            sB[idx >> 4][idx & 15] = Bm[l0 + idx];
            sC[idx >> 4][idx & 15] = Cm[l0 + idx];
        }
    }
    __syncthreads();

    // ---- exclusive chunk-prefix (replaces combine + h0buf) ----
    float h[16];
    #pragma unroll
    for (int n = 0; n < 16; ++n) h[n] = 0.f;
    {
        const float*  Sp = Ssum   + (size_t)b * NCH * D_INNER + d;
        const float4* Hp = (const float4*)(hlocal
                           + ((size_t)b * NCH * D_INNER + d) * 16);
        const size_t hstep = (size_t)D_INNER * 4;   // float4 stride per chunk
        if (fast) {
            #pragma unroll 2
            for (int cc = 0; cc < c; ++cc) {
                float S = Sp[(size_t)cc * D_INNER];
                const float4* hp = Hp + (size_t)cc * hstep;
                float4 v0 = hp[0], v1 = hp[1], v2 = hp[2], v3 = hp[3];
                float rp[16];
                pow_tree(__expf(S * An0), rp);
                h[0]  = rp[0]  * h[0]  + v0.x; h[1]  = rp[1]  * h[1]  + v0.y;
                h[2]  = rp[2]  * h[2]  + v0.z; h[3]  = rp[3]  * h[3]  + v0.w;
                h[4]  = rp[4]  * h[4]  + v1.x; h[5]  = rp[5]  * h[5]  + v1.y;
                h[6]  = rp[6]  * h[6]  + v1.z; h[7]  = rp[7]  * h[7]  + v1.w;
                h[8]  = rp[8]  * h[8]  + v2.x; h[9]  = rp[9]  * h[9]  + v2.y;
                h[10] = rp[10] * h[10] + v2.z; h[11] = rp[11] * h[11] + v2.w;
                h[12] = rp[12] * h[12] + v3.x; h[13] = rp[13] * h[13] + v3.y;
                h[14] = rp[14] * h[14] + v3.z; h[15] = rp[15] * h[15] + v3.w;
            }
        } else {
            for (int cc = 0; cc < c; ++cc) {
                float S = Sp[(size_t)cc * D_INNER];
                const float* hl = (const float*)(Hp + (size_t)cc * hstep);
                #pragma unroll
                for (int n = 0; n < 16; ++n)
                    h[n] = __expf(An[n] * S) * h[n] + hl[n];
            }
        }
    }
    const float Dv = Dp[d];

    size_t base = (size_t)(b * L_SEQ + c * CLEN) * D_INNER + d;
    float bd[PFD], bx[PFD], bg[PFD];
    #pragma unroll
    for (int i = 0; i < PFD; ++i) {
        bd[i] = (float)deltah[base + (size_t)i * D_INNER];
        bx[i] = (float)xch[base + (size_t)i * D_INNER];
        bg[i] = (float)sresh[base + (size_t)i * D_INNER];
    }

    if (fast) {
        for (int jb = 0; jb < CLEN; jb += PFD) {
            #pragma unroll
            for (int i = 0; i < PFD; ++i) {
                int j = jb + i;
                float dv = bd[i], xv = bx[i], gv = bg[i];
                int jn = j + PFD;
                if (jn < CLEN) {
                    bd[i] = (float)deltah[base + (size_t)jn * D_INNER];
                    bx[i] = (float)xch[base + (size_t)jn * D_INNER];
                    bg[i] = (float)sresh[base + (size_t)jn * D_INNER];
                }
                float dbx = dv * xv;
                float rp[16];
                pow_tree(__expf(dv * An0), rp);
                float y0 = 0.f, y1 = 0.f, y2 = 0.f, y3 = 0.f;
                #pragma unroll
                for (int n = 0; n < 16; n += 4) {
                    h[n]     = rp[n]     * h[n]     + dbx * sB[j][n];
                    h[n + 1] = rp[n + 1] * h[n + 1] + dbx * sB[j][n + 1];
                    h[n + 2] = rp[n + 2] * h[n + 2] + dbx * sB[j][n + 2];
                    h[n + 3] = rp[n + 3] * h[n + 3] + dbx * sB[j][n + 3];
                    y0 += h[n]     * sC[j][n];
                    y1 += h[n + 1] * sC[j][n + 1];
                    y2 += h[n + 2] * sC[j][n + 2];
                    y3 += h[n + 3] * sC[j][n + 3];
                }
                float y = (y0 + y1) + (y2 + y3);
                float yv = (y + xv * Dv) * gv;
                yhalf[base + (size_t)j * D_INNER] = (_Float16)yv;
            }
        }
    } else {
        for (int jb = 0; jb < CLEN; jb += PFD) {
            #pragma unroll
            for (int i = 0; i < PFD; ++i) {
                int j = jb + i;
                float dv = bd[i], xv = bx[i], gv = bg[i];
                int jn = j + PFD;
                if (jn < CLEN) {
                    bd[i] = (float)deltah[base + (size_t)jn * D_INNER];
                    bx[i] = (float)xch[base + (size_t)jn * D_INNER];
                    bg[i] = (float)sresh[base + (size_t)jn * D_INNER];
                }
                float dbx = dv * xv;
                float y = 0.f;
                #pragma unroll
                for (int n = 0; n < 16; ++n) {
                    h[n] = __expf(dv * An[n]) * h[n] + dbx * sB[j][n];
                    y += h[n] * sC[j][n];
                }
                float yv = (y + xv * Dv) * gv;
                yhalf[base + (size_t)j * D_INNER] = (_Float16)yv;
            }
        }
    }
}

extern "C" void kernel_launch(void* const* d_in, const int* in_sizes, int n_in,
                              void* d_out, int out_size, void* d_ws, size_t ws_size,
                              hipStream_t stream) {
    const float* x      = (const float*)d_in[0];
    const float* W_in   = (const float*)d_in[1];
    const float* conv_w = (const float*)d_in[2];
    const float* conv_b = (const float*)d_in[3];
    const float* W_x    = (const float*)d_in[4];
    const float* W_dt   = (const float*)d_in[5];
    const float* b_dt   = (const float*)d_in[6];
    const float* A_log  = (const float*)d_in[7];
    const float* D_par  = (const float*)d_in[8];
    const float* W_out  = (const float*)d_in[9];
    float* out = (float*)d_out;

    char* wsb = (char*)d_ws;
    _Float16*  xsh    = (_Float16*)(wsb + 0);             // 16,777,216 B
    _Float16*  sresh  = (_Float16*)(wsb + 16777216);      // 16,777,216 B
    _Float16*  deltah = (_Float16*)(wsb + 33554432);      // 16,777,216 B
    _Float16*  xch    = (_Float16*)(wsb + 50331648);      // 16,777,216 B
    _Float16*  xf16   = (_Float16*)(wsb + 67108864);      //  8,388,608 B (dead after K1)
    _Float16*  WinT   = (_Float16*)(wsb + 75497472);      //  8,388,608 B (dead after K1)
    _Float16*  yhalf  = (_Float16*)(wsb + 67108864);      // 16,777,216 B (aliases xf16+WinT)
    _Float16*  WxT    = (_Float16*)(wsb + 83886080);      //    393,216 B
    _Float16*  WdtT   = (_Float16*)(wsb + 84279296);      //    262,144 B
    // (xdh slot unused -- delta fused; h0buf slot unused -- combine fused)
    float*     Bbuf   = (float*)(wsb + 85065728);         //    262,144 B
    float*     Cbuf   = (float*)(wsb + 85327872);         //    262,144 B
    float*     Ssum   = (float*)(wsb + 85590016);         //  1,048,576 B
    float*     hloc   = (float*)(wsb + 86638592);         // 16,777,216 B
    _Float16*  WoutT  = (_Float16*)(wsb + 120193024);     //  4,194,304 B
    float*     cwT    = (float*)(wsb + 124387328);        //     32,768 B
    // end: 124,420,096 B

    dim3 blk(256);

    // 1. fused prep: all weight transposes + x cast + conv_w transpose
    prep<<<dim3(10561), blk, 0, stream>>>(x, xf16, W_in, WinT, W_x, WxT,
                                          W_dt, WdtT, W_out, WoutT, conv_w, cwT);
    // 2. K1: [xs fp16 | silu(res) fp16] = x @ W_in  (M=4096, N=4096, K=1024)
    gemm_k1<<<dim3(16, 16), dim3(512), 0, stream>>>(xf16, WinT, xsh, sresh);
    // 3. conv + SiLU -> xch fp16  (coalesced cwT weights)
    conv_silu<<<dim3((size_t)MM * D_INNER / 8 / 256), blk, 0, stream>>>(xsh, cwT, conv_b, xch);
    // 4. fused xd + delta: Bm/Cm fp32 + deltah fp16
    gemm_xd_delta<<<dim3(MM / 16), blk, 0, stream>>>(xch, WxT, WdtT, b_dt, Bbuf, Cbuf, deltah);
    // 5. scan pass 1  (NCH=64, CLEN=32)
    scan_part1<<<dim3(D_INNER / 256, NCH, B_SZ), blk, 0, stream>>>(deltah, xch, Bbuf, A_log, hloc, Ssum);
    // 6. scan pass 2 with fused chunk-prefix (+gating) -> yhalf fp16
    scan_part2<<<dim3(D_INNER / 256, NCH, B_SZ), blk, 0, stream>>>(deltah, xch, Bbuf, Cbuf, hloc, Ssum, A_log, D_par, sresh, yhalf);
    // 7. K5: out = y @ W_out  (M=4096, N=1024, K=2048)
    gemm_f16<0><<<dim3(8, 32), blk, 0, stream>>>(
        yhalf, WoutT, nullptr, out, nullptr, nullptr, MM, D_MODEL, D_INNER, D_MODEL);
}

// Round 13
// 291.972 us; speedup vs baseline: 1.1891x; 1.0883x over previous
//
#include <hip/hip_runtime.h>
#include <math.h>

#define B_SZ    2
#define L_SEQ   2048
#define D_MODEL 1024
#define D_INNER 2048
#define D_STATE 16
#define DT_RANK 64
#define MM      (B_SZ * L_SEQ)   // 4096 rows
#define NCH     64               // scan chunks (R8-proven: scan is latency-bound, needs TLP)
#define CLEN    (L_SEQ / NCH)    // 32 steps per chunk
#define PFD     8                // scan prefetch depth

typedef _Float16 h8v __attribute__((ext_vector_type(8)));
typedef _Float16 h4v __attribute__((ext_vector_type(4)));
typedef float f32x4 __attribute__((ext_vector_type(4)));

// Async global->LDS DMA, 16B per lane. LDS dest = uniform base + lane*16.
__device__ __forceinline__ void gload16(const void* g, void* l) {
    __builtin_amdgcn_global_load_lds((const __attribute__((address_space(1))) void*)g,
                                     (__attribute__((address_space(3))) void*)l, 16, 0, 0);
}

// r^(1..16) via repeated-squaring tree: depth <=4 (vs 16-deep serial fold).
__device__ __forceinline__ void pow_tree(float r1, float* rp) {
    float r2 = r1 * r1, r3 = r2 * r1, r4 = r2 * r2;
    float r8 = r4 * r4;
    rp[0] = r1;      rp[1] = r2;      rp[2] = r3;      rp[3] = r4;
    rp[4] = r4 * r1; rp[5] = r4 * r2; rp[6] = r4 * r3; rp[7] = r8;
    rp[8] = r8 * r1; rp[9] = r8 * r2; rp[10] = r8 * r3; rp[11] = r8 * r4;
    rp[12] = r8 * rp[4]; rp[13] = r8 * rp[5]; rp[14] = r8 * rp[6]; rp[15] = r8 * r8;
}

// ---------------------------------------------------------------------------
// prep: all weight transposes (fp32 -> fp16 T[N][K]) + x -> fp16 cast +
// conv_w transpose to [k][d] fp32.
// ---------------------------------------------------------------------------
__global__ __launch_bounds__(256) void prep(const float* __restrict__ x,
                                            _Float16* __restrict__ xf16,
                                            const float* __restrict__ W_in,
                                            _Float16* __restrict__ WinT,
                                            const float* __restrict__ W_x,
                                            _Float16* __restrict__ WxT,
                                            const float* __restrict__ W_dt,
                                            _Float16* __restrict__ WdtT,
                                            const float* __restrict__ W_out,
                                            _Float16* __restrict__ WoutT,
                                            const float* __restrict__ cw,
                                            float* __restrict__ cwT) {
    __shared__ float t[32][33];
    const int b = blockIdx.x;
    const float* W; _Float16* T; int K, N, tile;
    if (b < 4096)      { W = W_in;  T = WinT;  K = 1024; N = 4096; tile = b; }
    else if (b < 4288) { W = W_x;   T = WxT;   K = 2048; N = 96;   tile = b - 4096; }
    else if (b < 4416) { W = W_dt;  T = WdtT;  K = 64;   N = 2048; tile = b - 4288; }
    else if (b < 6464) { W = W_out; T = WoutT; K = 2048; N = 1024; tile = b - 4416; }
    else if (b < 10560) {
        int idx = (b - 6464) * 256 + threadIdx.x;
        float4 v = ((const float4*)x)[idx];
        h4v h = {(_Float16)v.x, (_Float16)v.y, (_Float16)v.z, (_Float16)v.w};
        *(h4v*)(xf16 + (size_t)idx * 4) = h;
        return;
    } else {
        // conv_w [2048][4] -> cwT [4][2048]
        for (int i = threadIdx.x; i < D_INNER * 4; i += 256) {
            int d = i >> 2, k = i & 3;
            cwT[k * D_INNER + d] = cw[i];
        }
        return;
    }
    const int ntx = N / 32;
    const int k0 = (tile / ntx) * 32, n0 = (tile % ntx) * 32;
    #pragma unroll
    for (int i = 0; i < 4; ++i) {
        int idx = threadIdx.x + i * 256;
        int r = idx >> 5, c = idx & 31;
        t[r][c] = W[(size_t)(k0 + r) * N + n0 + c];
    }
    __syncthreads();
    #pragma unroll
    for (int i = 0; i < 4; ++i) {
        int idx = threadIdx.x + i * 256;
        int n = idx >> 5, k = idx & 31;
        T[(size_t)(n0 + n) * K + k0 + k] = (_Float16)t[k][n];
    }
}

// ---------------------------------------------------------------------------
// K1 (R1 structure, best measured): 256x256 tile, BK=64, 8 waves (2Mx4N),
// double-buffered 2x64KiB LDS, 4 phases/K-tile x 16 MFMA.
// ANCHOR KERNEL: byte-frozen since R5; healthy-node band = 46-49us.
// Epilogue: cols<2048 -> H (xs); cols>=2048 -> silu -> Hg (gate).
// ---------------------------------------------------------------------------
#define LDA_(mi, ks) (*(const h8v*)(smb + cb_ + rowA + (mi) * 2048 + ((ks) ? ps1 : ps0)))
#define LDB_(ni, ks) (*(const h8v*)(smb + cb_ + 32768 + rowB + (ni) * 2048 + ((ks) ? ps1 : ps0)))
#define PH(m0, m1) \
    _Pragma("unroll") \
    for (int ni = 0; ni < 4; ++ni) { \
        acc[m0][ni] = __builtin_amdgcn_mfma_f32_16x16x32_f16(aF0, bF[2 * ni],     acc[m0][ni], 0, 0, 0); \
        acc[m0][ni] = __builtin_amdgcn_mfma_f32_16x16x32_f16(aF1, bF[2 * ni + 1], acc[m0][ni], 0, 0, 0); \
        acc[m1][ni] = __builtin_amdgcn_mfma_f32_16x16x32_f16(aF2, bF[2 * ni],     acc[m1][ni], 0, 0, 0); \
        acc[m1][ni] = __builtin_amdgcn_mfma_f32_16x16x32_f16(aF3, bF[2 * ni + 1], acc[m1][ni], 0, 0, 0); \
    }

__global__ __launch_bounds__(512, 2) void gemm_k1(const _Float16* __restrict__ A,
                                                  const _Float16* __restrict__ Bt,
                                                  _Float16* __restrict__ H,
                                                  _Float16* __restrict__ Hg) {
    // 128 KiB LDS: [A buf0 | B buf0 | A buf1 | B buf1], 32 KiB each.
    __shared__ _Float16 smem[65536];
    char* smb = (char*)smem;

    const int tid  = threadIdx.x;
    const int wave = tid >> 6, lane = tid & 63;
    const int wm = wave >> 2, wn = wave & 3;       // 2 x 4 wave grid
    const int lm = lane & 15, lq = lane >> 4;
    const int bm = blockIdx.y * 256, bn = blockIdx.x * 256;

    // read addressing: 16B k-slot s at physical slot s ^ (row&7); row&7 == lm&7
    const int ps0 = ((lq)     ^ (lm & 7)) << 4;
    const int ps1 = ((lq + 4) ^ (lm & 7)) << 4;
    const int rowA = (wm * 128 + lm) << 7;         // 128 B per row (BK=64 fp16)
    const int rowB = (wn * 64 + lm) << 7;

    // staging: LDS linear (wave*4+q)*1024 + lane*16 -> logical slot = (lane&7)^(lane>>3)
    const int srow  = lane >> 3;
    const int sslot = (lane & 7) ^ srow;
    const _Float16* pA = A  + (size_t)(bm + wave * 32 + srow) * 1024 + sslot * 8;
    const _Float16* pB = Bt + (size_t)(bn + wave * 32 + srow) * 1024 + sslot * 8;
    char* dA = smb + wave * 4096;                  // + buf*65536
    char* dB = smb + 32768 + wave * 4096;

    f32x4 acc[8][4];
    #pragma unroll
    for (int i = 0; i < 8; ++i)
        #pragma unroll
        for (int j = 0; j < 4; ++j) acc[i][j] = (f32x4){0.f, 0.f, 0.f, 0.f};

    // prologue: stage K-tile 0 into buf 0
    #pragma unroll
    for (int q = 0; q < 4; ++q) {
        gload16(pA + q * 8192, dA + q * 1024);
        gload16(pB + q * 8192, dB + q * 1024);
    }
    asm volatile("s_waitcnt vmcnt(0)" ::: "memory");
    __builtin_amdgcn_s_barrier();

    int cb_ = 0;
    for (int t = 0; t < 16; ++t) {
        const int nb_ = 65536 - cb_;
        const bool pf = (t < 15);
        const size_t kn = (size_t)(t + 1) * 64;    // next K-tile element offset

        h8v aF0, aF1, aF2, aF3;
        h8v bF[8];

        // ---- phase 1: mi 0,1 | read all 8 B-frags | stage next A-tile ----
        aF0 = LDA_(0, 0); aF1 = LDA_(0, 1); aF2 = LDA_(1, 0); aF3 = LDA_(1, 1);
        #pragma unroll
        for (int ni = 0; ni < 4; ++ni) { bF[2 * ni] = LDB_(ni, 0); bF[2 * ni + 1] = LDB_(ni, 1); }
        if (pf) {
            #pragma unroll
            for (int q = 0; q < 4; ++q) gload16(pA + kn + q * 8192, dA + nb_ + q * 1024);
        }
        __builtin_amdgcn_s_barrier();
        asm volatile("s_waitcnt lgkmcnt(0)" ::: "memory");
        __builtin_amdgcn_s_setprio(1);
        PH(0, 1);
        __builtin_amdgcn_s_setprio(0);
        __builtin_amdgcn_s_barrier();

        // ---- phase 2: mi 2,3 | stage next B-tile ----
        aF0 = LDA_(2, 0); aF1 = LDA_(2, 1); aF2 = LDA_(3, 0); aF3 = LDA_(3, 1);
        if (pf) {
            #pragma unroll
            for (int q = 0; q < 4; ++q) gload16(pB + kn + q * 8192, dB + nb_ + q * 1024);
        }
        __builtin_amdgcn_s_barrier();
        asm volatile("s_waitcnt lgkmcnt(0)" ::: "memory");
        __builtin_amdgcn_s_setprio(1);
        PH(2, 3);
        __builtin_amdgcn_s_setprio(0);
        __builtin_amdgcn_s_barrier();

        // ---- phase 3: mi 4,5 ----
        aF0 = LDA_(4, 0); aF1 = LDA_(4, 1); aF2 = LDA_(5, 0); aF3 = LDA_(5, 1);
        __builtin_amdgcn_s_barrier();
        asm volatile("s_waitcnt lgkmcnt(0)" ::: "memory");
        __builtin_amdgcn_s_setprio(1);
        PH(4, 5);
        __builtin_amdgcn_s_setprio(0);
        __builtin_amdgcn_s_barrier();

        // ---- phase 4: mi 6,7 | counted A'-wait pre-bar, B' drain post-MFMA ----
        aF0 = LDA_(6, 0); aF1 = LDA_(6, 1); aF2 = LDA_(7, 0); aF3 = LDA_(7, 1);
        asm volatile("s_waitcnt vmcnt(4)" ::: "memory");   // A' (issued P1) done
        __builtin_amdgcn_s_barrier();
        asm volatile("s_waitcnt lgkmcnt(0)" ::: "memory");
        __builtin_amdgcn_s_setprio(1);
        PH(6, 7);
        __builtin_amdgcn_s_setprio(0);
        asm volatile("s_waitcnt vmcnt(0)" ::: "memory");   // B' (issued P2) done
        __builtin_amdgcn_s_barrier();                      // -> next tile visible

        cb_ = nb_;
    }

    // epilogue: staging LDS is free; per-wave 16x72 fp16 transpose chunks
    _Float16* ep = smem + wave * 2048;
    const bool gate = (bn >= 2048);
    _Float16* dst = gate ? Hg : H;
    const int cbase = bn + wn * 64 - (gate ? 2048 : 0);
    #pragma unroll
    for (int mi = 0; mi < 8; ++mi) {
        #pragma unroll
        for (int ni = 0; ni < 4; ++ni)
            #pragma unroll
            for (int r = 0; r < 4; ++r) {
                float v = acc[mi][ni][r];
                if (gate) v = v / (1.f + __expf(-v));
                ep[(lq * 4 + r) * 72 + ni * 16 + lm] = (_Float16)v;
            }
        int rowb = bm + wm * 128 + mi * 16;
        #pragma unroll
        for (int i = 0; i < 2; ++i) {
            int ch = lane + 64 * i;
            int row = ch >> 3, c8 = (ch & 7) * 8;
            *(h8v*)&dst[(size_t)(rowb + row) * 2048 + cbase + c8] =
                *(const h8v*)&ep[row * 72 + c8];
        }
    }
}
#undef LDA_
#undef LDB_
#undef PH

// ---------------------------------------------------------------------------
// fp16 MFMA GEMM, double-buffered async DMA: C = A[M][K] @ Bt[N][K]^T.
// 128x128 tile, 256 thr, 4 waves 2x2, wave 64x64 (4x4 16x16x32 frags), BK=32.
// (retained for K5)  EPI 0: fp32 C.
// ---------------------------------------------------------------------------
template<int EPI>
__global__ __launch_bounds__(256) void gemm_f16(const _Float16* __restrict__ A,
                                                const _Float16* __restrict__ Bt,
                                                const float* __restrict__ bias,
                                                float* __restrict__ C,
                                                _Float16* __restrict__ H,
                                                _Float16* __restrict__ Hg,
                                                int M, int N, int K, int ldc) {
    __shared__ _Float16 smemh[16384];   // 32KB: staging dbuf, reused by epilogue

    const int tid = threadIdx.x;
    const int wave = tid >> 6, lane = tid & 63;
    const int bm = blockIdx.y * 128, bn = blockIdx.x * 128;

    const int lrow = lane >> 2, pc = lane & 3;
    const int ar = wave * 32 + lrow;
    const size_t gA = (size_t)(bm + ar) * K + ((pc ^ ((ar >> 1) & 3)) * 8);
    const size_t gB = (size_t)(bn + ar) * K + ((pc ^ ((ar >> 1) & 3)) * 8);
    const int lofs = (wave * 32) * 32;

    const int lm = lane & 15, lq = lane >> 4;
    const int rofs = (lq ^ ((lm >> 1) & 3)) * 8;
    const int wm = (wave >> 1) * 64, wn = (wave & 1) * 64;

    f32x4 acc[4][4];
    #pragma unroll
    for (int i = 0; i < 4; ++i)
        #pragma unroll
        for (int j = 0; j < 4; ++j) acc[i][j] = (f32x4){0.f, 0.f, 0.f, 0.f};

    // prologue: fill buffer 0  (A buf at kb*4096, B buf at 8192 + kb*4096)
    gload16(A + gA, smemh + lofs);
    gload16(A + gA + (size_t)16 * K, smemh + lofs + 16 * 32);
    gload16(Bt + gB, smemh + 8192 + lofs);
    gload16(Bt + gB + (size_t)16 * K, smemh + 8192 + lofs + 16 * 32);
    __syncthreads();

    int kb = 0;
    for (int k0 = 0; k0 < K; k0 += 32, kb ^= 1) {
        if (k0 + 32 < K) {   // issue next tile BEFORE computing this one
            int nb = kb ^ 1;
            gload16(A + gA + k0 + 32, smemh + nb * 4096 + lofs);
            gload16(A + gA + k0 + 32 + (size_t)16 * K, smemh + nb * 4096 + lofs + 16 * 32);
            gload16(Bt + gB + k0 + 32, smemh + 8192 + nb * 4096 + lofs);
            gload16(Bt + gB + k0 + 32 + (size_t)16 * K, smemh + 8192 + nb * 4096 + lofs + 16 * 32);
        }

        const _Float16* sA = smemh + kb * 4096;
        const _Float16* sB = smemh + 8192 + kb * 4096;
        h8v fa[4], fb[4];
        #pragma unroll
        for (int i = 0; i < 4; ++i) {
            fa[i] = *(const h8v*)&sA[(wm + i * 16 + lm) * 32 + rofs];
            fb[i] = *(const h8v*)&sB[(wn + i * 16 + lm) * 32 + rofs];
        }
        #pragma unroll
        for (int mi = 0; mi < 4; ++mi)
            #pragma unroll
            for (int ni = 0; ni < 4; ++ni)
                acc[mi][ni] = __builtin_amdgcn_mfma_f32_16x16x32_f16(fa[mi], fb[ni], acc[mi][ni], 0, 0, 0);
        __syncthreads();   // drains next-tile DMA; protects buffer reuse
    }
    // after final barrier all waves are done with staging LDS -> reuse it.

    if (EPI == 0) {
        float* ep = (float*)smemh + wave * 1088;   // 16 x 68 fp32 (padded)
        #pragma unroll
        for (int mi = 0; mi < 4; ++mi) {
            #pragma unroll
            for (int ni = 0; ni < 4; ++ni)
                #pragma unroll
                for (int r = 0; r < 4; ++r)
                    ep[(lq * 4 + r) * 68 + ni * 16 + lm] = acc[mi][ni][r];
            int rowb = bm + wm + mi * 16;
            #pragma unroll
            for (int i = 0; i < 4; ++i) {
                int ch = lane + 64 * i;
                int row = ch >> 4, c4 = (ch & 15) * 4;
                *(float4*)&C[(size_t)(rowb + row) * ldc + bn + wn + c4] =
                    *(const float4*)&ep[row * 68 + c4];
            }
        }
    } else {
        _Float16* ep = smemh + wave * 1152;        // 16 x 72 fp16 (padded, 16B rows)
        const bool gate = (EPI == 2) && (bn >= 2048);
        _Float16* dst = gate ? Hg : H;
        const int cb = bn + wn - (gate ? 2048 : 0);
        #pragma unroll
        for (int mi = 0; mi < 4; ++mi) {
            #pragma unroll
            for (int ni = 0; ni < 4; ++ni) {
                int col = bn + wn + ni * 16 + lm;
                #pragma unroll
                for (int r = 0; r < 4; ++r) {
                    float v = acc[mi][ni][r];
                    if (EPI == 1) {
                        float a = v + bias[col];
                        v = (a > 20.f) ? a : __logf(1.f + __expf(a));
                    } else if (gate) {
                        v = v / (1.f + __expf(-v));
                    }
                    ep[(lq * 4 + r) * 72 + ni * 16 + lm] = (_Float16)v;
                }
            }
            int rowb = bm + wm + mi * 16;
            #pragma unroll
            for (int i = 0; i < 2; ++i) {
                int ch = lane + 64 * i;
                int row = ch >> 3, c8 = (ch & 7) * 8;
                *(h8v*)&dst[(size_t)(rowb + row) * ldc + cb + c8] =
                    *(const h8v*)&ep[row * 72 + c8];
            }
        }
    }
}

// ---------------------------------------------------------------------------
// Fused xd + delta kernel (R9): per block (16 rows, 256 blocks):
//   phase 1: xd[16][96] = xch_rows @ WxT^T (4-wave K-split, LDS reduction);
//   phase 2: delta[16][2048] = softplus(xd @ WdtT^T + b_dt) (4-wave N-split).
// ---------------------------------------------------------------------------
__global__ __launch_bounds__(256) void gemm_xd_delta(const _Float16* __restrict__ xch,
                                                     const _Float16* __restrict__ WxT,
                                                     const _Float16* __restrict__ WdtT,
                                                     const float* __restrict__ b_dt,
                                                     float* __restrict__ Bm,
                                                     float* __restrict__ Cm,
                                                     _Float16* __restrict__ deltah) {
    __shared__ float sred[3][64][25];       // waves 1..3 partials (6 frags x 4), +1 pad
    __shared__ _Float16 xd16[16 * 72];      // xd rows (padded: 144B rows, 16B-aligned)
    __shared__ _Float16 epd[4][16 * 72];    // per-wave delta transpose staging
    const int tid = threadIdx.x;
    const int wave = tid >> 6, lane = tid & 63;
    const int lm = lane & 15, lq = lane >> 4;
    const int m0 = blockIdx.x * 16;

    // ---------------- phase 1: xd (K-split) ----------------
    const int kbase = wave * 512;
    const _Float16* pa = xch + (size_t)(m0 + lm) * D_INNER + kbase + lq * 8;
    const _Float16* pb = WxT + (size_t)lm * D_INNER + kbase + lq * 8;

    f32x4 acc[6];
    #pragma unroll
    for (int i = 0; i < 6; ++i) acc[i] = (f32x4){0.f, 0.f, 0.f, 0.f};

    #pragma unroll 2
    for (int it = 0; it < 16; ++it) {
        const int ko = it * 32;
        h8v fa = *(const h8v*)(pa + ko);
        #pragma unroll
        for (int nf = 0; nf < 6; ++nf) {
            h8v fb = *(const h8v*)(pb + (size_t)nf * 16 * D_INNER + ko);
            acc[nf] = __builtin_amdgcn_mfma_f32_16x16x32_f16(fa, fb, acc[nf], 0, 0, 0);
        }
    }

    if (wave != 0) {
        #pragma unroll
        for (int nf = 0; nf < 6; ++nf)
            #pragma unroll
            for (int r = 0; r < 4; ++r)
                sred[wave - 1][lane][nf * 4 + r] = acc[nf][r];
    }
    __syncthreads();
    if (wave == 0) {
        #pragma unroll
        for (int nf = 0; nf < 6; ++nf) {
            int col = nf * 16 + lm;
            #pragma unroll
            for (int r = 0; r < 4; ++r) {
                float v = ((acc[nf][r] + sred[0][lane][nf * 4 + r])
                           + sred[1][lane][nf * 4 + r]) + sred[2][lane][nf * 4 + r];
                int row = lq * 4 + r;               // block-local row
                if (nf < 4)        xd16[row * 72 + col] = (_Float16)v;
                else if (col < 80) Bm[(size_t)(m0 + row) * 16 + (col - 64)] = v;
                else               Cm[(size_t)(m0 + row) * 16 + (col - 80)] = v;
            }
        }
    }
    __syncthreads();

    // ---------------- phase 2: delta (N-split) ----------------
    h8v fa0 = *(const h8v*)&xd16[lm * 72 + lq * 8];        // k 0..31
    h8v fa1 = *(const h8v*)&xd16[lm * 72 + 32 + lq * 8];   // k 32..63
    const int nbase = wave * 512;
    _Float16* ep = epd[wave];

    #pragma unroll 1
    for (int g = 0; g < 8; ++g) {          // groups of 4 n-tiles (64 cols)
        #pragma unroll
        for (int t = 0; t < 4; ++t) {
            const int col = nbase + g * 64 + t * 16 + lm;
            const _Float16* wrow = WdtT + (size_t)col * 64;
            h8v fb0 = *(const h8v*)(wrow + lq * 8);
            h8v fb1 = *(const h8v*)(wrow + 32 + lq * 8);
            f32x4 a = __builtin_amdgcn_mfma_f32_16x16x32_f16(fa0, fb0,
                        (f32x4){0.f, 0.f, 0.f, 0.f}, 0, 0, 0);
            a = __builtin_amdgcn_mfma_f32_16x16x32_f16(fa1, fb1, a, 0, 0, 0);
            const float bv = b_dt[col];
            #pragma unroll
            for (int r = 0; r < 4; ++r) {
                float v = a[r] + bv;
                v = (v > 20.f) ? v : __logf(1.f + __expf(v));
                ep[(lq * 4 + r) * 72 + t * 16 + lm] = (_Float16)v;
            }
        }
        // wave-synchronous LDS transpose -> 16B stores
        #pragma unroll
        for (int i = 0; i < 2; ++i) {
            int ch = lane + 64 * i;
            int row = ch >> 3, c8 = (ch & 7) * 8;
            *(h8v*)&deltah[(size_t)(m0 + row) * D_INNER + nbase + g * 64 + c8] =
                *(const h8v*)&ep[row * 72 + c8];
        }
    }
}

// ---------------------------------------------------------------------------
// Depthwise causal conv (k=4) + bias + SiLU, 8 elements/thread.
// ---------------------------------------------------------------------------
__global__ __launch_bounds__(256) void conv_silu(const _Float16* __restrict__ xsh,
                                                 const float* __restrict__ cwT,
                                                 const float* __restrict__ cb,
                                                 _Float16* __restrict__ xch) {
    int idx = blockIdx.x * 256 + threadIdx.x;
    int d0 = (idx * 8) & (D_INNER - 1);
    int m  = (idx * 8) >> 11;
    int l  = m & (L_SEQ - 1);
    float acc[8];
    {
        float4 c0 = *(const float4*)&cb[d0];
        float4 c1 = *(const float4*)&cb[d0 + 4];
        acc[0] = c0.x; acc[1] = c0.y; acc[2] = c0.z; acc[3] = c0.w;
        acc[4] = c1.x; acc[5] = c1.y; acc[6] = c1.z; acc[7] = c1.w;
    }
    #pragma unroll
    for (int k = 0; k < 4; ++k) {
        int ll = l - 3 + k;
        if (ll >= 0) {
            h8v v = *(const h8v*)(xsh + (size_t)(m - 3 + k) * D_INNER + d0);
            float4 w0 = *(const float4*)&cwT[k * D_INNER + d0];
            float4 w1 = *(const float4*)&cwT[k * D_INNER + d0 + 4];
            acc[0] += (float)v[0] * w0.x; acc[1] += (float)v[1] * w0.y;
            acc[2] += (float)v[2] * w0.z; acc[3] += (float)v[3] * w0.w;
            acc[4] += (float)v[4] * w1.x; acc[5] += (float)v[5] * w1.y;
            acc[6] += (float)v[6] * w1.z; acc[7] += (float)v[7] * w1.w;
        }
    }
    h8v o;
    #pragma unroll
    for (int j = 0; j < 8; ++j) {
        float s = acc[j] / (1.f + __expf(-acc[j]));
        o[j] = (_Float16)s;
    }
    *(h8v*)(xch + (size_t)idx * 8) = o;
}

// ---------------------------------------------------------------------------
// Scan pass 1: per (b, chunk, d) chunk-local final state (h0=0) + S=sum(delta).
// Fast path uses pow_tree (R8).
// ---------------------------------------------------------------------------
__global__ __launch_bounds__(256) void scan_part1(const _Float16* __restrict__ deltah,
                                                  const _Float16* __restrict__ xch,
                                                  const float* __restrict__ Bm,
                                                  const float* __restrict__ A_log,
                                                  float* __restrict__ hlocal,
                                                  float* __restrict__ Ssum) {
    const int t = threadIdx.x;
    const int d = blockIdx.x * 256 + t;
    const int c = blockIdx.y;
    const int b = blockIdx.z;

    float An[16];
    {
        const float4* ap = (const float4*)(A_log + (size_t)d * 16);
        #pragma unroll
        for (int q = 0; q < 4; ++q) {
            float4 v = ap[q];
            An[q * 4 + 0] = -__expf(v.x); An[q * 4 + 1] = -__expf(v.y);
            An[q * 4 + 2] = -__expf(v.z); An[q * 4 + 3] = -__expf(v.w);
        }
    }
    const float An0 = An[0];
    bool fast = An0 < 0.f;
    #pragma unroll
    for (int n = 0; n < 16; ++n)
        fast = fast && (fabsf(An[n] - (float)(n + 1) * An0) < 1e-3f * fabsf(An[n]));

    __shared__ float sB[CLEN][16];
    {
        size_t l0 = (size_t)(b * L_SEQ + c * CLEN) * 16;
        #pragma unroll
        for (int i = 0; i < (CLEN * 16) / 256; ++i) {
            int idx = t + i * 256;
            sB[idx >> 4][idx & 15] = Bm[l0 + idx];
        }
    }
    __syncthreads();

    float h[16];
    #pragma unroll
    for (int n = 0; n < 16; ++n) h[n] = 0.f;
    float S = 0.f;

    size_t base = (size_t)(b * L_SEQ + c * CLEN) * D_INNER + d;
    float bd[PFD], bx[PFD];
    #pragma unroll
    for (int i = 0; i < PFD; ++i) {
        bd[i] = (float)deltah[base + (size_t)i * D_INNER];
        bx[i] = (float)xch[base + (size_t)i * D_INNER];
    }

    if (fast) {
        for (int jb = 0; jb < CLEN; jb += PFD) {
            #pragma unroll
            for (int i = 0; i < PFD; ++i) {
                int j = jb + i;
                float dv = bd[i], xv = bx[i];
                int jn = j + PFD;
                if (jn < CLEN) {
                    bd[i] = (float)deltah[base + (size_t)jn * D_INNER];
                    bx[i] = (float)xch[base + (size_t)jn * D_INNER];
                }
                S += dv;
                float dbx = dv * xv;
                float rp[16];
                pow_tree(__expf(dv * An0), rp);
                #pragma unroll
                for (int n = 0; n < 16; ++n)
                    h[n] = rp[n] * h[n] + dbx * sB[j][n];
            }
        }
    } else {
        for (int jb = 0; jb < CLEN; jb += PFD) {
            #pragma unroll
            for (int i = 0; i < PFD; ++i) {
                int j = jb + i;
                float dv = bd[i], xv = bx[i];
                int jn = j + PFD;
                if (jn < CLEN) {
                    bd[i] = (float)deltah[base + (size_t)jn * D_INNER];
                    bx[i] = (float)xch[base + (size_t)jn * D_INNER];
                }
                S += dv;
                float dbx = dv * xv;
                #pragma unroll
                for (int n = 0; n < 16; ++n)
                    h[n] = __expf(dv * An[n]) * h[n] + dbx * sB[j][n];
            }
        }
    }

    size_t o = ((size_t)(b * NCH + c) * D_INNER + d) * 16;
    float4* hp = (float4*)(hlocal + o);
    #pragma unroll
    for (int q = 0; q < 4; ++q)
        hp[q] = make_float4(h[q * 4], h[q * 4 + 1], h[q * 4 + 2], h[q * 4 + 3]);
    Ssum[(size_t)(b * NCH + c) * D_INNER + d] = S;
}

// ---------------------------------------------------------------------------
// Combine: sequential over NCH chunks per (b,d,n); writes each chunk's h0.
// (R13: restored -- the fused in-sp2 prefix was latency-bound O(NCH^2) and
// cost +28us vs this kernel's ~20us; scan is latency-structured.)
// ---------------------------------------------------------------------------
__global__ __launch_bounds__(256) void scan_combine(const float* __restrict__ hlocal,
                                                    const float* __restrict__ Ssum,
                                                    const float* __restrict__ A_log,
                                                    float* __restrict__ h0buf) {
    int gid = blockIdx.x * 256 + threadIdx.x;
    int n = gid & 15;
    int d = (gid >> 4) & (D_INNER - 1);
    int b = gid >> 15;
    float An = -__expf(A_log[(size_t)d * 16 + n]);
    float H = 0.f;
    float pS[4], pH[4];
    #pragma unroll
    for (int i = 0; i < 4; ++i) {
        size_t sc = (size_t)(b * NCH + i) * D_INNER + d;
        pS[i] = Ssum[sc];
        pH[i] = hlocal[sc * 16 + n];
    }
    for (int cb = 0; cb < NCH; cb += 4) {
        #pragma unroll
        for (int i = 0; i < 4; ++i) {
            int c = cb + i;
            float S = pS[i], hl = pH[i];
            int cn = c + 4;
            if (cn < NCH) {
                size_t sc = (size_t)(b * NCH + cn) * D_INNER + d;
                pS[i] = Ssum[sc];
                pH[i] = hlocal[sc * 16 + n];
            }
            size_t o = ((size_t)(b * NCH + c) * D_INNER + d) * 16 + n;
            h0buf[o] = H;
            H = __expf(An * S) * H + hl;
        }
    }
}

// ---------------------------------------------------------------------------
// Scan pass 2: replay from h0; y = sum_n h*C; fuse +xc*D and *pre-silu'd gate;
// write y fp16. Fast path: pow_tree + 4-partial y dot (R8).
// ---------------------------------------------------------------------------
__global__ __launch_bounds__(256) void scan_part2(const _Float16* __restrict__ deltah,
                                                  const _Float16* __restrict__ xch,
                                                  const float* __restrict__ Bm,
                                                  const float* __restrict__ Cm,
                                                  const float* __restrict__ h0buf,
                                                  const float* __restrict__ A_log,
                                                  const float* __restrict__ Dp,
                                                  const _Float16* __restrict__ sresh,
                                                  _Float16* __restrict__ yhalf) {
    const int t = threadIdx.x;
    const int d = blockIdx.x * 256 + t;
    const int c = blockIdx.y;
    const int b = blockIdx.z;

    float An[16];
    {
        const float4* ap = (const float4*)(A_log + (size_t)d * 16);
        #pragma unroll
        for (int q = 0; q < 4; ++q) {
            float4 v = ap[q];
            An[q * 4 + 0] = -__expf(v.x); An[q * 4 + 1] = -__expf(v.y);
            An[q * 4 + 2] = -__expf(v.z); An[q * 4 + 3] = -__expf(v.w);
        }
    }
    const float An0 = An[0];
    bool fast = An0 < 0.f;
    #pragma unroll
    for (int n = 0; n < 16; ++n)
        fast = fast && (fabsf(An[n] - (float)(n + 1) * An0) < 1e-3f * fabsf(An[n]));

    __shared__ float sB[CLEN][16];
    __shared__ float sC[CLEN][16];
    {
        size_t l0 = (size_t)(b * L_SEQ + c * CLEN) * 16;
        #pragma unroll
        for (int i = 0; i < (CLEN * 16) / 256; ++i) {
            int idx = t + i * 256;
            sB[idx >> 4][idx & 15] = Bm[l0 + idx];
            sC[idx >> 4][idx & 15] = Cm[l0 + idx];
        }
    }
    __syncthreads();

    float h[16];
    {
        size_t o = ((size_t)(b * NCH + c) * D_INNER + d) * 16;
        const float4* hp = (const float4*)(h0buf + o);
        #pragma unroll
        for (int q = 0; q < 4; ++q) {
            float4 v = hp[q];
            h[q * 4 + 0] = v.x; h[q * 4 + 1] = v.y;
            h[q * 4 + 2] = v.z; h[q * 4 + 3] = v.w;
        }
    }
    const float Dv = Dp[d];

    size_t base = (size_t)(b * L_SEQ + c * CLEN) * D_INNER + d;
    float bd[PFD], bx[PFD], bg[PFD];
    #pragma unroll
    for (int i = 0; i < PFD; ++i) {
        bd[i] = (float)deltah[base + (size_t)i * D_INNER];
        bx[i] = (float)xch[base + (size_t)i * D_INNER];
        bg[i] = (float)sresh[base + (size_t)i * D_INNER];
    }

    if (fast) {
        for (int jb = 0; jb < CLEN; jb += PFD) {
            #pragma unroll
            for (int i = 0; i < PFD; ++i) {
                int j = jb + i;
                float dv = bd[i], xv = bx[i], gv = bg[i];
                int jn = j + PFD;
                if (jn < CLEN) {
                    bd[i] = (float)deltah[base + (size_t)jn * D_INNER];
                    bx[i] = (float)xch[base + (size_t)jn * D_INNER];
                    bg[i] = (float)sresh[base + (size_t)jn * D_INNER];
                }
                float dbx = dv * xv;
                float rp[16];
                pow_tree(__expf(dv * An0), rp);
                float y0 = 0.f, y1 = 0.f, y2 = 0.f, y3 = 0.f;
                #pragma unroll
                for (int n = 0; n < 16; n += 4) {
                    h[n]     = rp[n]     * h[n]     + dbx * sB[j][n];
                    h[n + 1] = rp[n + 1] * h[n + 1] + dbx * sB[j][n + 1];
                    h[n + 2] = rp[n + 2] * h[n + 2] + dbx * sB[j][n + 2];
                    h[n + 3] = rp[n + 3] * h[n + 3] + dbx * sB[j][n + 3];
                    y0 += h[n]     * sC[j][n];
                    y1 += h[n + 1] * sC[j][n + 1];
                    y2 += h[n + 2] * sC[j][n + 2];
                    y3 += h[n + 3] * sC[j][n + 3];
                }
                float y = (y0 + y1) + (y2 + y3);
                float yv = (y + xv * Dv) * gv;
                yhalf[base + (size_t)j * D_INNER] = (_Float16)yv;
            }
        }
    } else {
        for (int jb = 0; jb < CLEN; jb += PFD) {
            #pragma unroll
            for (int i = 0; i < PFD; ++i) {
                int j = jb + i;
                float dv = bd[i], xv = bx[i], gv = bg[i];
                int jn = j + PFD;
                if (jn < CLEN) {
                    bd[i] = (float)deltah[base + (size_t)jn * D_INNER];
                    bx[i] = (float)xch[base + (size_t)jn * D_INNER];
                    bg[i] = (float)sresh[base + (size_t)jn * D_INNER];
                }
                float dbx = dv * xv;
                float y = 0.f;
                #pragma unroll
                for (int n = 0; n < 16; ++n) {
                    h[n] = __expf(dv * An[n]) * h[n] + dbx * sB[j][n];
                    y += h[n] * sC[j][n];
                }
                float yv = (y + xv * Dv) * gv;
                yhalf[base + (size_t)j * D_INNER] = (_Float16)yv;
            }
        }
    }
}

extern "C" void kernel_launch(void* const* d_in, const int* in_sizes, int n_in,
                              void* d_out, int out_size, void* d_ws, size_t ws_size,
                              hipStream_t stream) {
    const float* x      = (const float*)d_in[0];
    const float* W_in   = (const float*)d_in[1];
    const float* conv_w = (const float*)d_in[2];
    const float* conv_b = (const float*)d_in[3];
    const float* W_x    = (const float*)d_in[4];
    const float* W_dt   = (const float*)d_in[5];
    const float* b_dt   = (const float*)d_in[6];
    const float* A_log  = (const float*)d_in[7];
    const float* D_par  = (const float*)d_in[8];
    const float* W_out  = (const float*)d_in[9];
    float* out = (float*)d_out;

    char* wsb = (char*)d_ws;
    _Float16*  xsh    = (_Float16*)(wsb + 0);             // 16,777,216 B
    _Float16*  sresh  = (_Float16*)(wsb + 16777216);      // 16,777,216 B
    _Float16*  deltah = (_Float16*)(wsb + 33554432);      // 16,777,216 B
    _Float16*  xch    = (_Float16*)(wsb + 50331648);      // 16,777,216 B
    _Float16*  xf16   = (_Float16*)(wsb + 67108864);      //  8,388,608 B (dead after K1)
    _Float16*  WinT   = (_Float16*)(wsb + 75497472);      //  8,388,608 B (dead after K1)
    _Float16*  yhalf  = (_Float16*)(wsb + 67108864);      // 16,777,216 B (aliases xf16+WinT)
    _Float16*  WxT    = (_Float16*)(wsb + 83886080);      //    393,216 B
    _Float16*  WdtT   = (_Float16*)(wsb + 84279296);      //    262,144 B
    float*     Bbuf   = (float*)(wsb + 85065728);         //    262,144 B
    float*     Cbuf   = (float*)(wsb + 85327872);         //    262,144 B
    float*     Ssum   = (float*)(wsb + 85590016);         //  1,048,576 B
    float*     hloc   = (float*)(wsb + 86638592);         // 16,777,216 B
    float*     h0buf  = (float*)(wsb + 103415808);        // 16,777,216 B (restored)
    _Float16*  WoutT  = (_Float16*)(wsb + 120193024);     //  4,194,304 B
    float*     cwT    = (float*)(wsb + 124387328);        //     32,768 B
    // end: 124,420,096 B

    dim3 blk(256);

    // 1. fused prep: all weight transposes + x cast + conv_w transpose
    prep<<<dim3(10561), blk, 0, stream>>>(x, xf16, W_in, WinT, W_x, WxT,
                                          W_dt, WdtT, W_out, WoutT, conv_w, cwT);
    // 2. K1: [xs fp16 | silu(res) fp16] = x @ W_in  (M=4096, N=4096, K=1024)
    gemm_k1<<<dim3(16, 16), dim3(512), 0, stream>>>(xf16, WinT, xsh, sresh);
    // 3. conv + SiLU -> xch fp16  (coalesced cwT weights)
    conv_silu<<<dim3((size_t)MM * D_INNER / 8 / 256), blk, 0, stream>>>(xsh, cwT, conv_b, xch);
    // 4. fused xd + delta: Bm/Cm fp32 + deltah fp16
    gemm_xd_delta<<<dim3(MM / 16), blk, 0, stream>>>(xch, WxT, WdtT, b_dt, Bbuf, Cbuf, deltah);
    // 5. scan pass 1  (NCH=64, CLEN=32)
    scan_part1<<<dim3(D_INNER / 256, NCH, B_SZ), blk, 0, stream>>>(deltah, xch, Bbuf, A_log, hloc, Ssum);
    // 6. combine (restored R13)
    scan_combine<<<dim3(B_SZ * D_INNER * 16 / 256), blk, 0, stream>>>(hloc, Ssum, A_log, h0buf);
    // 7. scan pass 2 (+gating) -> yhalf fp16
    scan_part2<<<dim3(D_INNER / 256, NCH, B_SZ), blk, 0, stream>>>(deltah, xch, Bbuf, Cbuf, h0buf, A_log, D_par, sresh, yhalf);
    // 8. K5: out = y @ W_out  (M=4096, N=1024, K=2048)
    gemm_f16<0><<<dim3(8, 32), blk, 0, stream>>>(
        yhalf, WoutT, nullptr, out, nullptr, nullptr, MM, D_MODEL, D_INNER, D_MODEL);
}

// Round 14
// 276.749 us; speedup vs baseline: 1.2545x; 1.0550x over previous
//
#include <hip/hip_runtime.h>
#include <math.h>

#define B_SZ    2
#define L_SEQ   2048
#define D_MODEL 1024
#define D_INNER 2048
#define D_STATE 16
#define DT_RANK 64
#define MM      (B_SZ * L_SEQ)   // 4096 rows
#define NCH     64               // scan chunks
#define CLEN    (L_SEQ / NCH)    // 32 steps per chunk
#define PFD     8                // scan prefetch depth

typedef _Float16 h8v __attribute__((ext_vector_type(8)));
typedef _Float16 h4v __attribute__((ext_vector_type(4)));
typedef _Float16 h2v __attribute__((ext_vector_type(2)));
typedef float f32x4 __attribute__((ext_vector_type(4)));

// Async global->LDS DMA, 16B per lane. LDS dest = uniform base + lane*16.
__device__ __forceinline__ void gload16(const void* g, void* l) {
    __builtin_amdgcn_global_load_lds((const __attribute__((address_space(1))) void*)g,
                                     (__attribute__((address_space(3))) void*)l, 16, 0, 0);
}

// r^(1..16) via repeated-squaring tree: depth <=4 (vs 16-deep serial fold).
__device__ __forceinline__ void pow_tree(float r1, float* rp) {
    float r2 = r1 * r1, r3 = r2 * r1, r4 = r2 * r2;
    float r8 = r4 * r4;
    rp[0] = r1;      rp[1] = r2;      rp[2] = r3;      rp[3] = r4;
    rp[4] = r4 * r1; rp[5] = r4 * r2; rp[6] = r4 * r3; rp[7] = r8;
    rp[8] = r8 * r1; rp[9] = r8 * r2; rp[10] = r8 * r3; rp[11] = r8 * r4;
    rp[12] = r8 * rp[4]; rp[13] = r8 * rp[5]; rp[14] = r8 * rp[6]; rp[15] = r8 * r8;
}

// ---------------------------------------------------------------------------
// prep: all weight transposes (fp32 -> fp16 T[N][K]) + x -> fp16 cast +
// conv_w transpose to [k][d] fp32.
// ---------------------------------------------------------------------------
__global__ __launch_bounds__(256) void prep(const float* __restrict__ x,
                                            _Float16* __restrict__ xf16,
                                            const float* __restrict__ W_in,
                                            _Float16* __restrict__ WinT,
                                            const float* __restrict__ W_x,
                                            _Float16* __restrict__ WxT,
                                            const float* __restrict__ W_dt,
                                            _Float16* __restrict__ WdtT,
                                            const float* __restrict__ W_out,
                                            _Float16* __restrict__ WoutT,
                                            const float* __restrict__ cw,
                                            float* __restrict__ cwT) {
    __shared__ float t[32][33];
    const int b = blockIdx.x;
    const float* W; _Float16* T; int K, N, tile;
    if (b < 4096)      { W = W_in;  T = WinT;  K = 1024; N = 4096; tile = b; }
    else if (b < 4288) { W = W_x;   T = WxT;   K = 2048; N = 96;   tile = b - 4096; }
    else if (b < 4416) { W = W_dt;  T = WdtT;  K = 64;   N = 2048; tile = b - 4288; }
    else if (b < 6464) { W = W_out; T = WoutT; K = 2048; N = 1024; tile = b - 4416; }
    else if (b < 10560) {
        int idx = (b - 6464) * 256 + threadIdx.x;
        float4 v = ((const float4*)x)[idx];
        h4v h = {(_Float16)v.x, (_Float16)v.y, (_Float16)v.z, (_Float16)v.w};
        *(h4v*)(xf16 + (size_t)idx * 4) = h;
        return;
    } else {
        // conv_w [2048][4] -> cwT [4][2048]
        for (int i = threadIdx.x; i < D_INNER * 4; i += 256) {
            int d = i >> 2, k = i & 3;
            cwT[k * D_INNER + d] = cw[i];
        }
        return;
    }
    const int ntx = N / 32;
    const int k0 = (tile / ntx) * 32, n0 = (tile % ntx) * 32;
    #pragma unroll
    for (int i = 0; i < 4; ++i) {
        int idx = threadIdx.x + i * 256;
        int r = idx >> 5, c = idx & 31;
        t[r][c] = W[(size_t)(k0 + r) * N + n0 + c];
    }
    __syncthreads();
    #pragma unroll
    for (int i = 0; i < 4; ++i) {
        int idx = threadIdx.x + i * 256;
        int n = idx >> 5, k = idx & 31;
        T[(size_t)(n0 + n) * K + k0 + k] = (_Float16)t[k][n];
    }
}

// ---------------------------------------------------------------------------
// K1 (R1 structure, best measured): 256x256 tile, BK=64, 8 waves (2Mx4N),
// double-buffered 2x64KiB LDS, 4 phases/K-tile x 16 MFMA.
// ANCHOR KERNEL: byte-frozen since R5; healthy-node band = 46-49us.
// Epilogue: cols<2048 -> H (xs); cols>=2048 -> silu -> Hg (gate).
// ---------------------------------------------------------------------------
#define LDA_(mi, ks) (*(const h8v*)(smb + cb_ + rowA + (mi) * 2048 + ((ks) ? ps1 : ps0)))
#define LDB_(ni, ks) (*(const h8v*)(smb + cb_ + 32768 + rowB + (ni) * 2048 + ((ks) ? ps1 : ps0)))
#define PH(m0, m1) \
    _Pragma("unroll") \
    for (int ni = 0; ni < 4; ++ni) { \
        acc[m0][ni] = __builtin_amdgcn_mfma_f32_16x16x32_f16(aF0, bF[2 * ni],     acc[m0][ni], 0, 0, 0); \
        acc[m0][ni] = __builtin_amdgcn_mfma_f32_16x16x32_f16(aF1, bF[2 * ni + 1], acc[m0][ni], 0, 0, 0); \
        acc[m1][ni] = __builtin_amdgcn_mfma_f32_16x16x32_f16(aF2, bF[2 * ni],     acc[m1][ni], 0, 0, 0); \
        acc[m1][ni] = __builtin_amdgcn_mfma_f32_16x16x32_f16(aF3, bF[2 * ni + 1], acc[m1][ni], 0, 0, 0); \
    }

__global__ __launch_bounds__(512, 2) void gemm_k1(const _Float16* __restrict__ A,
                                                  const _Float16* __restrict__ Bt,
                                                  _Float16* __restrict__ H,
                                                  _Float16* __restrict__ Hg) {
    // 128 KiB LDS: [A buf0 | B buf0 | A buf1 | B buf1], 32 KiB each.
    __shared__ _Float16 smem[65536];
    char* smb = (char*)smem;

    const int tid  = threadIdx.x;
    const int wave = tid >> 6, lane = tid & 63;
    const int wm = wave >> 2, wn = wave & 3;       // 2 x 4 wave grid
    const int lm = lane & 15, lq = lane >> 4;
    const int bm = blockIdx.y * 256, bn = blockIdx.x * 256;

    // read addressing: 16B k-slot s at physical slot s ^ (row&7); row&7 == lm&7
    const int ps0 = ((lq)     ^ (lm & 7)) << 4;
    const int ps1 = ((lq + 4) ^ (lm & 7)) << 4;
    const int rowA = (wm * 128 + lm) << 7;         // 128 B per row (BK=64 fp16)
    const int rowB = (wn * 64 + lm) << 7;

    // staging: LDS linear (wave*4+q)*1024 + lane*16 -> logical slot = (lane&7)^(lane>>3)
    const int srow  = lane >> 3;
    const int sslot = (lane & 7) ^ srow;
    const _Float16* pA = A  + (size_t)(bm + wave * 32 + srow) * 1024 + sslot * 8;
    const _Float16* pB = Bt + (size_t)(bn + wave * 32 + srow) * 1024 + sslot * 8;
    char* dA = smb + wave * 4096;                  // + buf*65536
    char* dB = smb + 32768 + wave * 4096;

    f32x4 acc[8][4];
    #pragma unroll
    for (int i = 0; i < 8; ++i)
        #pragma unroll
        for (int j = 0; j < 4; ++j) acc[i][j] = (f32x4){0.f, 0.f, 0.f, 0.f};

    // prologue: stage K-tile 0 into buf 0
    #pragma unroll
    for (int q = 0; q < 4; ++q) {
        gload16(pA + q * 8192, dA + q * 1024);
        gload16(pB + q * 8192, dB + q * 1024);
    }
    asm volatile("s_waitcnt vmcnt(0)" ::: "memory");
    __builtin_amdgcn_s_barrier();

    int cb_ = 0;
    for (int t = 0; t < 16; ++t) {
        const int nb_ = 65536 - cb_;
        const bool pf = (t < 15);
        const size_t kn = (size_t)(t + 1) * 64;    // next K-tile element offset

        h8v aF0, aF1, aF2, aF3;
        h8v bF[8];

        // ---- phase 1: mi 0,1 | read all 8 B-frags | stage next A-tile ----
        aF0 = LDA_(0, 0); aF1 = LDA_(0, 1); aF2 = LDA_(1, 0); aF3 = LDA_(1, 1);
        #pragma unroll
        for (int ni = 0; ni < 4; ++ni) { bF[2 * ni] = LDB_(ni, 0); bF[2 * ni + 1] = LDB_(ni, 1); }
        if (pf) {
            #pragma unroll
            for (int q = 0; q < 4; ++q) gload16(pA + kn + q * 8192, dA + nb_ + q * 1024);
        }
        __builtin_amdgcn_s_barrier();
        asm volatile("s_waitcnt lgkmcnt(0)" ::: "memory");
        __builtin_amdgcn_s_setprio(1);
        PH(0, 1);
        __builtin_amdgcn_s_setprio(0);
        __builtin_amdgcn_s_barrier();

        // ---- phase 2: mi 2,3 | stage next B-tile ----
        aF0 = LDA_(2, 0); aF1 = LDA_(2, 1); aF2 = LDA_(3, 0); aF3 = LDA_(3, 1);
        if (pf) {
            #pragma unroll
            for (int q = 0; q < 4; ++q) gload16(pB + kn + q * 8192, dB + nb_ + q * 1024);
        }
        __builtin_amdgcn_s_barrier();
        asm volatile("s_waitcnt lgkmcnt(0)" ::: "memory");
        __builtin_amdgcn_s_setprio(1);
        PH(2, 3);
        __builtin_amdgcn_s_setprio(0);
        __builtin_amdgcn_s_barrier();

        // ---- phase 3: mi 4,5 ----
        aF0 = LDA_(4, 0); aF1 = LDA_(4, 1); aF2 = LDA_(5, 0); aF3 = LDA_(5, 1);
        __builtin_amdgcn_s_barrier();
        asm volatile("s_waitcnt lgkmcnt(0)" ::: "memory");
        __builtin_amdgcn_s_setprio(1);
        PH(4, 5);
        __builtin_amdgcn_s_setprio(0);
        __builtin_amdgcn_s_barrier();

        // ---- phase 4: mi 6,7 | counted A'-wait pre-bar, B' drain post-MFMA ----
        aF0 = LDA_(6, 0); aF1 = LDA_(6, 1); aF2 = LDA_(7, 0); aF3 = LDA_(7, 1);
        asm volatile("s_waitcnt vmcnt(4)" ::: "memory");   // A' (issued P1) done
        __builtin_amdgcn_s_barrier();
        asm volatile("s_waitcnt lgkmcnt(0)" ::: "memory");
        __builtin_amdgcn_s_setprio(1);
        PH(6, 7);
        __builtin_amdgcn_s_setprio(0);
        asm volatile("s_waitcnt vmcnt(0)" ::: "memory");   // B' (issued P2) done
        __builtin_amdgcn_s_barrier();                      // -> next tile visible

        cb_ = nb_;
    }

    // epilogue: staging LDS is free; per-wave 16x72 fp16 transpose chunks
    _Float16* ep = smem + wave * 2048;
    const bool gate = (bn >= 2048);
    _Float16* dst = gate ? Hg : H;
    const int cbase = bn + wn * 64 - (gate ? 2048 : 0);
    #pragma unroll
    for (int mi = 0; mi < 8; ++mi) {
        #pragma unroll
        for (int ni = 0; ni < 4; ++ni)
            #pragma unroll
            for (int r = 0; r < 4; ++r) {
                float v = acc[mi][ni][r];
                if (gate) v = v / (1.f + __expf(-v));
                ep[(lq * 4 + r) * 72 + ni * 16 + lm] = (_Float16)v;
            }
        int rowb = bm + wm * 128 + mi * 16;
        #pragma unroll
        for (int i = 0; i < 2; ++i) {
            int ch = lane + 64 * i;
            int row = ch >> 3, c8 = (ch & 7) * 8;
            *(h8v*)&dst[(size_t)(rowb + row) * 2048 + cbase + c8] =
                *(const h8v*)&ep[row * 72 + c8];
        }
    }
}
#undef LDA_
#undef LDB_
#undef PH

// ---------------------------------------------------------------------------
// fp16 MFMA GEMM, double-buffered async DMA: C = A[M][K] @ Bt[N][K]^T.
// 128x128 tile, 256 thr, 4 waves 2x2, wave 64x64 (4x4 16x16x32 frags), BK=32.
// (retained for K5)  EPI 0: fp32 C.
// ---------------------------------------------------------------------------
template<int EPI>
__global__ __launch_bounds__(256) void gemm_f16(const _Float16* __restrict__ A,
                                                const _Float16* __restrict__ Bt,
                                                const float* __restrict__ bias,
                                                float* __restrict__ C,
                                                _Float16* __restrict__ H,
                                                _Float16* __restrict__ Hg,
                                                int M, int N, int K, int ldc) {
    __shared__ _Float16 smemh[16384];   // 32KB: staging dbuf, reused by epilogue

    const int tid = threadIdx.x;
    const int wave = tid >> 6, lane = tid & 63;
    const int bm = blockIdx.y * 128, bn = blockIdx.x * 128;

    const int lrow = lane >> 2, pc = lane & 3;
    const int ar = wave * 32 + lrow;
    const size_t gA = (size_t)(bm + ar) * K + ((pc ^ ((ar >> 1) & 3)) * 8);
    const size_t gB = (size_t)(bn + ar) * K + ((pc ^ ((ar >> 1) & 3)) * 8);
    const int lofs = (wave * 32) * 32;

    const int lm = lane & 15, lq = lane >> 4;
    const int rofs = (lq ^ ((lm >> 1) & 3)) * 8;
    const int wm = (wave >> 1) * 64, wn = (wave & 1) * 64;

    f32x4 acc[4][4];
    #pragma unroll
    for (int i = 0; i < 4; ++i)
        #pragma unroll
        for (int j = 0; j < 4; ++j) acc[i][j] = (f32x4){0.f, 0.f, 0.f, 0.f};

    // prologue: fill buffer 0  (A buf at kb*4096, B buf at 8192 + kb*4096)
    gload16(A + gA, smemh + lofs);
    gload16(A + gA + (size_t)16 * K, smemh + lofs + 16 * 32);
    gload16(Bt + gB, smemh + 8192 + lofs);
    gload16(Bt + gB + (size_t)16 * K, smemh + 8192 + lofs + 16 * 32);
    __syncthreads();

    int kb = 0;
    for (int k0 = 0; k0 < K; k0 += 32, kb ^= 1) {
        if (k0 + 32 < K) {   // issue next tile BEFORE computing this one
            int nb = kb ^ 1;
            gload16(A + gA + k0 + 32, smemh + nb * 4096 + lofs);
            gload16(A + gA + k0 + 32 + (size_t)16 * K, smemh + nb * 4096 + lofs + 16 * 32);
            gload16(Bt + gB + k0 + 32, smemh + 8192 + nb * 4096 + lofs);
            gload16(Bt + gB + k0 + 32 + (size_t)16 * K, smemh + 8192 + nb * 4096 + lofs + 16 * 32);
        }

        const _Float16* sA = smemh + kb * 4096;
        const _Float16* sB = smemh + 8192 + kb * 4096;
        h8v fa[4], fb[4];
        #pragma unroll
        for (int i = 0; i < 4; ++i) {
            fa[i] = *(const h8v*)&sA[(wm + i * 16 + lm) * 32 + rofs];
            fb[i] = *(const h8v*)&sB[(wn + i * 16 + lm) * 32 + rofs];
        }
        #pragma unroll
        for (int mi = 0; mi < 4; ++mi)
            #pragma unroll
            for (int ni = 0; ni < 4; ++ni)
                acc[mi][ni] = __builtin_amdgcn_mfma_f32_16x16x32_f16(fa[mi], fb[ni], acc[mi][ni], 0, 0, 0);
        __syncthreads();   // drains next-tile DMA; protects buffer reuse
    }
    // after final barrier all waves are done with staging LDS -> reuse it.

    if (EPI == 0) {
        float* ep = (float*)smemh + wave * 1088;   // 16 x 68 fp32 (padded)
        #pragma unroll
        for (int mi = 0; mi < 4; ++mi) {
            #pragma unroll
            for (int ni = 0; ni < 4; ++ni)
                #pragma unroll
                for (int r = 0; r < 4; ++r)
                    ep[(lq * 4 + r) * 68 + ni * 16 + lm] = acc[mi][ni][r];
            int rowb = bm + wm + mi * 16;
            #pragma unroll
            for (int i = 0; i < 4; ++i) {
                int ch = lane + 64 * i;
                int row = ch >> 4, c4 = (ch & 15) * 4;
                *(float4*)&C[(size_t)(rowb + row) * ldc + bn + wn + c4] =
                    *(const float4*)&ep[row * 68 + c4];
            }
        }
    } else {
        _Float16* ep = smemh + wave * 1152;        // 16 x 72 fp16 (padded, 16B rows)
        const bool gate = (EPI == 2) && (bn >= 2048);
        _Float16* dst = gate ? Hg : H;
        const int cb = bn + wn - (gate ? 2048 : 0);
        #pragma unroll
        for (int mi = 0; mi < 4; ++mi) {
            #pragma unroll
            for (int ni = 0; ni < 4; ++ni) {
                int col = bn + wn + ni * 16 + lm;
                #pragma unroll
                for (int r = 0; r < 4; ++r) {
                    float v = acc[mi][ni][r];
                    if (EPI == 1) {
                        float a = v + bias[col];
                        v = (a > 20.f) ? a : __logf(1.f + __expf(a));
                    } else if (gate) {
                        v = v / (1.f + __expf(-v));
                    }
                    ep[(lq * 4 + r) * 72 + ni * 16 + lm] = (_Float16)v;
                }
            }
            int rowb = bm + wm + mi * 16;
            #pragma unroll
            for (int i = 0; i < 2; ++i) {
                int ch = lane + 64 * i;
                int row = ch >> 3, c8 = (ch & 7) * 8;
                *(h8v*)&dst[(size_t)(rowb + row) * ldc + cb + c8] =
                    *(const h8v*)&ep[row * 72 + c8];
            }
        }
    }
}

// ---------------------------------------------------------------------------
// Fused xd + delta kernel (R9): per block (16 rows, 256 blocks):
//   phase 1: xd[16][96] = xch_rows @ WxT^T (4-wave K-split, LDS reduction);
//   phase 2: delta[16][2048] = softplus(xd @ WdtT^T + b_dt) (4-wave N-split).
// ---------------------------------------------------------------------------
__global__ __launch_bounds__(256) void gemm_xd_delta(const _Float16* __restrict__ xch,
                                                     const _Float16* __restrict__ WxT,
                                                     const _Float16* __restrict__ WdtT,
                                                     const float* __restrict__ b_dt,
                                                     float* __restrict__ Bm,
                                                     float* __restrict__ Cm,
                                                     _Float16* __restrict__ deltah) {
    __shared__ float sred[3][64][25];       // waves 1..3 partials (6 frags x 4), +1 pad
    __shared__ _Float16 xd16[16 * 72];      // xd rows (padded: 144B rows, 16B-aligned)
    __shared__ _Float16 epd[4][16 * 72];    // per-wave delta transpose staging
    const int tid = threadIdx.x;
    const int wave = tid >> 6, lane = tid & 63;
    const int lm = lane & 15, lq = lane >> 4;
    const int m0 = blockIdx.x * 16;

    // ---------------- phase 1: xd (K-split) ----------------
    const int kbase = wave * 512;
    const _Float16* pa = xch + (size_t)(m0 + lm) * D_INNER + kbase + lq * 8;
    const _Float16* pb = WxT + (size_t)lm * D_INNER + kbase + lq * 8;

    f32x4 acc[6];
    #pragma unroll
    for (int i = 0; i < 6; ++i) acc[i] = (f32x4){0.f, 0.f, 0.f, 0.f};

    #pragma unroll 2
    for (int it = 0; it < 16; ++it) {
        const int ko = it * 32;
        h8v fa = *(const h8v*)(pa + ko);
        #pragma unroll
        for (int nf = 0; nf < 6; ++nf) {
            h8v fb = *(const h8v*)(pb + (size_t)nf * 16 * D_INNER + ko);
            acc[nf] = __builtin_amdgcn_mfma_f32_16x16x32_f16(fa, fb, acc[nf], 0, 0, 0);
        }
    }

    if (wave != 0) {
        #pragma unroll
        for (int nf = 0; nf < 6; ++nf)
            #pragma unroll
            for (int r = 0; r < 4; ++r)
                sred[wave - 1][lane][nf * 4 + r] = acc[nf][r];
    }
    __syncthreads();
    if (wave == 0) {
        #pragma unroll
        for (int nf = 0; nf < 6; ++nf) {
            int col = nf * 16 + lm;
            #pragma unroll
            for (int r = 0; r < 4; ++r) {
                float v = ((acc[nf][r] + sred[0][lane][nf * 4 + r])
                           + sred[1][lane][nf * 4 + r]) + sred[2][lane][nf * 4 + r];
                int row = lq * 4 + r;               // block-local row
                if (nf < 4)        xd16[row * 72 + col] = (_Float16)v;
                else if (col < 80) Bm[(size_t)(m0 + row) * 16 + (col - 64)] = v;
                else               Cm[(size_t)(m0 + row) * 16 + (col - 80)] = v;
            }
        }
    }
    __syncthreads();

    // ---------------- phase 2: delta (N-split) ----------------
    h8v fa0 = *(const h8v*)&xd16[lm * 72 + lq * 8];        // k 0..31
    h8v fa1 = *(const h8v*)&xd16[lm * 72 + 32 + lq * 8];   // k 32..63
    const int nbase = wave * 512;
    _Float16* ep = epd[wave];

    #pragma unroll 1
    for (int g = 0; g < 8; ++g) {          // groups of 4 n-tiles (64 cols)
        #pragma unroll
        for (int t = 0; t < 4; ++t) {
            const int col = nbase + g * 64 + t * 16 + lm;
            const _Float16* wrow = WdtT + (size_t)col * 64;
            h8v fb0 = *(const h8v*)(wrow + lq * 8);
            h8v fb1 = *(const h8v*)(wrow + 32 + lq * 8);
            f32x4 a = __builtin_amdgcn_mfma_f32_16x16x32_f16(fa0, fb0,
                        (f32x4){0.f, 0.f, 0.f, 0.f}, 0, 0, 0);
            a = __builtin_amdgcn_mfma_f32_16x16x32_f16(fa1, fb1, a, 0, 0, 0);
            const float bv = b_dt[col];
            #pragma unroll
            for (int r = 0; r < 4; ++r) {
                float v = a[r] + bv;
                v = (v > 20.f) ? v : __logf(1.f + __expf(v));
                ep[(lq * 4 + r) * 72 + t * 16 + lm] = (_Float16)v;
            }
        }
        // wave-synchronous LDS transpose -> 16B stores
        #pragma unroll
        for (int i = 0; i < 2; ++i) {
            int ch = lane + 64 * i;
            int row = ch >> 3, c8 = (ch & 7) * 8;
            *(h8v*)&deltah[(size_t)(m0 + row) * D_INNER + nbase + g * 64 + c8] =
                *(const h8v*)&ep[row * 72 + c8];
        }
    }
}

// ---------------------------------------------------------------------------
// Depthwise causal conv (k=4) + bias + SiLU, 8 elements/thread.
// ---------------------------------------------------------------------------
__global__ __launch_bounds__(256) void conv_silu(const _Float16* __restrict__ xsh,
                                                 const float* __restrict__ cwT,
                                                 const float* __restrict__ cb,
                                                 _Float16* __restrict__ xch) {
    int idx = blockIdx.x * 256 + threadIdx.x;
    int d0 = (idx * 8) & (D_INNER - 1);
    int m  = (idx * 8) >> 11;
    int l  = m & (L_SEQ - 1);
    float acc[8];
    {
        float4 c0 = *(const float4*)&cb[d0];
        float4 c1 = *(const float4*)&cb[d0 + 4];
        acc[0] = c0.x; acc[1] = c0.y; acc[2] = c0.z; acc[3] = c0.w;
        acc[4] = c1.x; acc[5] = c1.y; acc[6] = c1.z; acc[7] = c1.w;
    }
    #pragma unroll
    for (int k = 0; k < 4; ++k) {
        int ll = l - 3 + k;
        if (ll >= 0) {
            h8v v = *(const h8v*)(xsh + (size_t)(m - 3 + k) * D_INNER + d0);
            float4 w0 = *(const float4*)&cwT[k * D_INNER + d0];
            float4 w1 = *(const float4*)&cwT[k * D_INNER + d0 + 4];
            acc[0] += (float)v[0] * w0.x; acc[1] += (float)v[1] * w0.y;
            acc[2] += (float)v[2] * w0.z; acc[3] += (float)v[3] * w0.w;
            acc[4] += (float)v[4] * w1.x; acc[5] += (float)v[5] * w1.y;
            acc[6] += (float)v[6] * w1.z; acc[7] += (float)v[7] * w1.w;
        }
    }
    h8v o;
    #pragma unroll
    for (int j = 0; j < 8; ++j) {
        float s = acc[j] / (1.f + __expf(-acc[j]));
        o[j] = (_Float16)s;
    }
    *(h8v*)(xch + (size_t)idx * 8) = o;
}

// ---------------------------------------------------------------------------
// Scan pass 1 (R14: 2 channels/thread): thread t owns d0=blk*512+2t and d0+1.
// Two independent h-recurrence chains interleave in one instruction stream
// (fills the ~60% idle VALU slots R7/R12 counters showed); streamed loads
// become one 4B h2v instead of two 2B scalars. Per-d math unchanged.
// ---------------------------------------------------------------------------
__global__ __launch_bounds__(256) void scan_part1(const _Float16* __restrict__ deltah,
                                                  const _Float16* __restrict__ xch,
                                                  const float* __restrict__ Bm,
                                                  const float* __restrict__ A_log,
                                                  float* __restrict__ hlocal,
                                                  float* __restrict__ Ssum) {
    const int t = threadIdx.x;
    const int d0 = blockIdx.x * 512 + 2 * t;   // even
    const int c = blockIdx.y;
    const int b = blockIdx.z;

    float An[2][16];
    #pragma unroll
    for (int s = 0; s < 2; ++s) {
        const float4* ap = (const float4*)(A_log + (size_t)(d0 + s) * 16);
        #pragma unroll
        for (int q = 0; q < 4; ++q) {
            float4 v = ap[q];
            An[s][q * 4 + 0] = -__expf(v.x); An[s][q * 4 + 1] = -__expf(v.y);
            An[s][q * 4 + 2] = -__expf(v.z); An[s][q * 4 + 3] = -__expf(v.w);
        }
    }
    const float A00 = An[0][0], A10 = An[1][0];
    bool fast = (A00 < 0.f) && (A10 < 0.f);
    #pragma unroll
    for (int n = 0; n < 16; ++n) {
        fast = fast && (fabsf(An[0][n] - (float)(n + 1) * A00) < 1e-3f * fabsf(An[0][n]));
        fast = fast && (fabsf(An[1][n] - (float)(n + 1) * A10) < 1e-3f * fabsf(An[1][n]));
    }

    __shared__ float sB[CLEN][16];
    {
        size_t l0 = (size_t)(b * L_SEQ + c * CLEN) * 16;
        #pragma unroll
        for (int i = 0; i < (CLEN * 16) / 256; ++i) {
            int idx = t + i * 256;
            sB[idx >> 4][idx & 15] = Bm[l0 + idx];
        }
    }
    __syncthreads();

    float h[2][16];
    #pragma unroll
    for (int n = 0; n < 16; ++n) { h[0][n] = 0.f; h[1][n] = 0.f; }
    float S0 = 0.f, S1 = 0.f;

    size_t base = (size_t)(b * L_SEQ + c * CLEN) * D_INNER + d0;
    h2v bd[PFD], bx[PFD];
    #pragma unroll
    for (int i = 0; i < PFD; ++i) {
        bd[i] = *(const h2v*)(deltah + base + (size_t)i * D_INNER);
        bx[i] = *(const h2v*)(xch    + base + (size_t)i * D_INNER);
    }

    if (fast) {
        for (int jb = 0; jb < CLEN; jb += PFD) {
            #pragma unroll
            for (int i = 0; i < PFD; ++i) {
                int j = jb + i;
                float dv0 = (float)bd[i][0], dv1 = (float)bd[i][1];
                float xv0 = (float)bx[i][0], xv1 = (float)bx[i][1];
                int jn = j + PFD;
                if (jn < CLEN) {
                    bd[i] = *(const h2v*)(deltah + base + (size_t)jn * D_INNER);
                    bx[i] = *(const h2v*)(xch    + base + (size_t)jn * D_INNER);
                }
                S0 += dv0; S1 += dv1;
                float dbx0 = dv0 * xv0, dbx1 = dv1 * xv1;
                float rp0[16], rp1[16];
                pow_tree(__expf(dv0 * A00), rp0);
                pow_tree(__expf(dv1 * A10), rp1);
                #pragma unroll
                for (int n = 0; n < 16; ++n) {
                    h[0][n] = rp0[n] * h[0][n] + dbx0 * sB[j][n];
                    h[1][n] = rp1[n] * h[1][n] + dbx1 * sB[j][n];
                }
            }
        }
    } else {
        for (int jb = 0; jb < CLEN; jb += PFD) {
            #pragma unroll
            for (int i = 0; i < PFD; ++i) {
                int j = jb + i;
                float dv0 = (float)bd[i][0], dv1 = (float)bd[i][1];
                float xv0 = (float)bx[i][0], xv1 = (float)bx[i][1];
                int jn = j + PFD;
                if (jn < CLEN) {
                    bd[i] = *(const h2v*)(deltah + base + (size_t)jn * D_INNER);
                    bx[i] = *(const h2v*)(xch    + base + (size_t)jn * D_INNER);
                }
                S0 += dv0; S1 += dv1;
                float dbx0 = dv0 * xv0, dbx1 = dv1 * xv1;
                #pragma unroll
                for (int n = 0; n < 16; ++n) {
                    h[0][n] = __expf(dv0 * An[0][n]) * h[0][n] + dbx0 * sB[j][n];
                    h[1][n] = __expf(dv1 * An[1][n]) * h[1][n] + dbx1 * sB[j][n];
                }
            }
        }
    }

    #pragma unroll
    for (int s = 0; s < 2; ++s) {
        size_t o = ((size_t)(b * NCH + c) * D_INNER + d0 + s) * 16;
        float4* hp = (float4*)(hlocal + o);
        #pragma unroll
        for (int q = 0; q < 4; ++q)
            hp[q] = make_float4(h[s][q * 4], h[s][q * 4 + 1], h[s][q * 4 + 2], h[s][q * 4 + 3]);
    }
    Ssum[(size_t)(b * NCH + c) * D_INNER + d0]     = S0;
    Ssum[(size_t)(b * NCH + c) * D_INNER + d0 + 1] = S1;
}

// ---------------------------------------------------------------------------
// Combine: sequential over NCH chunks per (b,d,n); writes each chunk's h0.
// (unchanged; proven R13)
// ---------------------------------------------------------------------------
__global__ __launch_bounds__(256) void scan_combine(const float* __restrict__ hlocal,
                                                    const float* __restrict__ Ssum,
                                                    const float* __restrict__ A_log,
                                                    float* __restrict__ h0buf) {
    int gid = blockIdx.x * 256 + threadIdx.x;
    int n = gid & 15;
    int d = (gid >> 4) & (D_INNER - 1);
    int b = gid >> 15;
    float An = -__expf(A_log[(size_t)d * 16 + n]);
    float H = 0.f;
    float pS[4], pH[4];
    #pragma unroll
    for (int i = 0; i < 4; ++i) {
        size_t sc = (size_t)(b * NCH + i) * D_INNER + d;
        pS[i] = Ssum[sc];
        pH[i] = hlocal[sc * 16 + n];
    }
    for (int cb = 0; cb < NCH; cb += 4) {
        #pragma unroll
        for (int i = 0; i < 4; ++i) {
            int c = cb + i;
            float S = pS[i], hl = pH[i];
            int cn = c + 4;
            if (cn < NCH) {
                size_t sc = (size_t)(b * NCH + cn) * D_INNER + d;
                pS[i] = Ssum[sc];
                pH[i] = hlocal[sc * 16 + n];
            }
            size_t o = ((size_t)(b * NCH + c) * D_INNER + d) * 16 + n;
            h0buf[o] = H;
            H = __expf(An * S) * H + hl;
        }
    }
}

// ---------------------------------------------------------------------------
// Scan pass 2 (R14: 2 channels/thread, same scheme as scan_part1): replay
// from h0; y = sum_n h*C; fuse +xc*D and *pre-silu'd gate; yhalf as h2v.
// ---------------------------------------------------------------------------
__global__ __launch_bounds__(256) void scan_part2(const _Float16* __restrict__ deltah,
                                                  const _Float16* __restrict__ xch,
                                                  const float* __restrict__ Bm,
                                                  const float* __restrict__ Cm,
                                                  const float* __restrict__ h0buf,
                                                  const float* __restrict__ A_log,
                                                  const float* __restrict__ Dp,
                                                  const _Float16* __restrict__ sresh,
                                                  _Float16* __restrict__ yhalf) {
    const int t = threadIdx.x;
    const int d0 = blockIdx.x * 512 + 2 * t;   // even
    const int c = blockIdx.y;
    const int b = blockIdx.z;

    float An[2][16];
    #pragma unroll
    for (int s = 0; s < 2; ++s) {
        const float4* ap = (const float4*)(A_log + (size_t)(d0 + s) * 16);
        #pragma unroll
        for (int q = 0; q < 4; ++q) {
            float4 v = ap[q];
            An[s][q * 4 + 0] = -__expf(v.x); An[s][q * 4 + 1] = -__expf(v.y);
            An[s][q * 4 + 2] = -__expf(v.z); An[s][q * 4 + 3] = -__expf(v.w);
        }
    }
    const float A00 = An[0][0], A10 = An[1][0];
    bool fast = (A00 < 0.f) && (A10 < 0.f);
    #pragma unroll
    for (int n = 0; n < 16; ++n) {
        fast = fast && (fabsf(An[0][n] - (float)(n + 1) * A00) < 1e-3f * fabsf(An[0][n]));
        fast = fast && (fabsf(An[1][n] - (float)(n + 1) * A10) < 1e-3f * fabsf(An[1][n]));
    }

    __shared__ float sB[CLEN][16];
    __shared__ float sC[CLEN][16];
    {
        size_t l0 = (size_t)(b * L_SEQ + c * CLEN) * 16;
        #pragma unroll
        for (int i = 0; i < (CLEN * 16) / 256; ++i) {
            int idx = t + i * 256;
            sB[idx >> 4][idx & 15] = Bm[l0 + idx];
            sC[idx >> 4][idx & 15] = Cm[l0 + idx];
        }
    }
    __syncthreads();

    float h[2][16];
    #pragma unroll
    for (int s = 0; s < 2; ++s) {
        size_t o = ((size_t)(b * NCH + c) * D_INNER + d0 + s) * 16;
        const float4* hp = (const float4*)(h0buf + o);
        #pragma unroll
        for (int q = 0; q < 4; ++q) {
            float4 v = hp[q];
            h[s][q * 4 + 0] = v.x; h[s][q * 4 + 1] = v.y;
            h[s][q * 4 + 2] = v.z; h[s][q * 4 + 3] = v.w;
        }
    }
    const float Dv0 = Dp[d0], Dv1 = Dp[d0 + 1];

    size_t base = (size_t)(b * L_SEQ + c * CLEN) * D_INNER + d0;
    h2v bd[PFD], bx[PFD], bg[PFD];
    #pragma unroll
    for (int i = 0; i < PFD; ++i) {
        bd[i] = *(const h2v*)(deltah + base + (size_t)i * D_INNER);
        bx[i] = *(const h2v*)(xch    + base + (size_t)i * D_INNER);
        bg[i] = *(const h2v*)(sresh  + base + (size_t)i * D_INNER);
    }

    if (fast) {
        for (int jb = 0; jb < CLEN; jb += PFD) {
            #pragma unroll
            for (int i = 0; i < PFD; ++i) {
                int j = jb + i;
                float dv0 = (float)bd[i][0], dv1 = (float)bd[i][1];
                float xv0 = (float)bx[i][0], xv1 = (float)bx[i][1];
                float gv0 = (float)bg[i][0], gv1 = (float)bg[i][1];
                int jn = j + PFD;
                if (jn < CLEN) {
                    bd[i] = *(const h2v*)(deltah + base + (size_t)jn * D_INNER);
                    bx[i] = *(const h2v*)(xch    + base + (size_t)jn * D_INNER);
                    bg[i] = *(const h2v*)(sresh  + base + (size_t)jn * D_INNER);
                }
                float dbx0 = dv0 * xv0, dbx1 = dv1 * xv1;
                float rp0[16], rp1[16];
                pow_tree(__expf(dv0 * A00), rp0);
                pow_tree(__expf(dv1 * A10), rp1);
                float y0a = 0.f, y0b = 0.f, y1a = 0.f, y1b = 0.f;
                #pragma unroll
                for (int n = 0; n < 16; n += 2) {
                    h[0][n]     = rp0[n]     * h[0][n]     + dbx0 * sB[j][n];
                    h[1][n]     = rp1[n]     * h[1][n]     + dbx1 * sB[j][n];
                    h[0][n + 1] = rp0[n + 1] * h[0][n + 1] + dbx0 * sB[j][n + 1];
                    h[1][n + 1] = rp1[n + 1] * h[1][n + 1] + dbx1 * sB[j][n + 1];
                    y0a += h[0][n]     * sC[j][n];
                    y1a += h[1][n]     * sC[j][n];
                    y0b += h[0][n + 1] * sC[j][n + 1];
                    y1b += h[1][n + 1] * sC[j][n + 1];
                }
                float yv0 = ((y0a + y0b) + xv0 * Dv0) * gv0;
                float yv1 = ((y1a + y1b) + xv1 * Dv1) * gv1;
                h2v outv; outv[0] = (_Float16)yv0; outv[1] = (_Float16)yv1;
                *(h2v*)(yhalf + base + (size_t)j * D_INNER) = outv;
            }
        }
    } else {
        for (int jb = 0; jb < CLEN; jb += PFD) {
            #pragma unroll
            for (int i = 0; i < PFD; ++i) {
                int j = jb + i;
                float dv0 = (float)bd[i][0], dv1 = (float)bd[i][1];
                float xv0 = (float)bx[i][0], xv1 = (float)bx[i][1];
                float gv0 = (float)bg[i][0], gv1 = (float)bg[i][1];
                int jn = j + PFD;
                if (jn < CLEN) {
                    bd[i] = *(const h2v*)(deltah + base + (size_t)jn * D_INNER);
                    bx[i] = *(const h2v*)(xch    + base + (size_t)jn * D_INNER);
                    bg[i] = *(const h2v*)(sresh  + base + (size_t)jn * D_INNER);
                }
                float dbx0 = dv0 * xv0, dbx1 = dv1 * xv1;
                float y0 = 0.f, y1 = 0.f;
                #pragma unroll
                for (int n = 0; n < 16; ++n) {
                    h[0][n] = __expf(dv0 * An[0][n]) * h[0][n] + dbx0 * sB[j][n];
                    h[1][n] = __expf(dv1 * An[1][n]) * h[1][n] + dbx1 * sB[j][n];
                    y0 += h[0][n] * sC[j][n];
                    y1 += h[1][n] * sC[j][n];
                }
                float yv0 = (y0 + xv0 * Dv0) * gv0;
                float yv1 = (y1 + xv1 * Dv1) * gv1;
                h2v outv; outv[0] = (_Float16)yv0; outv[1] = (_Float16)yv1;
                *(h2v*)(yhalf + base + (size_t)j * D_INNER) = outv;
            }
        }
    }
}

extern "C" void kernel_launch(void* const* d_in, const int* in_sizes, int n_in,
                              void* d_out, int out_size, void* d_ws, size_t ws_size,
                              hipStream_t stream) {
    const float* x      = (const float*)d_in[0];
    const float* W_in   = (const float*)d_in[1];
    const float* conv_w = (const float*)d_in[2];
    const float* conv_b = (const float*)d_in[3];
    const float* W_x    = (const float*)d_in[4];
    const float* W_dt   = (const float*)d_in[5];
    const float* b_dt   = (const float*)d_in[6];
    const float* A_log  = (const float*)d_in[7];
    const float* D_par  = (const float*)d_in[8];
    const float* W_out  = (const float*)d_in[9];
    float* out = (float*)d_out;

    char* wsb = (char*)d_ws;
    _Float16*  xsh    = (_Float16*)(wsb + 0);             // 16,777,216 B
    _Float16*  sresh  = (_Float16*)(wsb + 16777216);      // 16,777,216 B
    _Float16*  deltah = (_Float16*)(wsb + 33554432);      // 16,777,216 B
    _Float16*  xch    = (_Float16*)(wsb + 50331648);      // 16,777,216 B
    _Float16*  xf16   = (_Float16*)(wsb + 67108864);      //  8,388,608 B (dead after K1)
    _Float16*  WinT   = (_Float16*)(wsb + 75497472);      //  8,388,608 B (dead after K1)
    _Float16*  yhalf  = (_Float16*)(wsb + 67108864);      // 16,777,216 B (aliases xf16+WinT)
    _Float16*  WxT    = (_Float16*)(wsb + 83886080);      //    393,216 B
    _Float16*  WdtT   = (_Float16*)(wsb + 84279296);      //    262,144 B
    float*     Bbuf   = (float*)(wsb + 85065728);         //    262,144 B
    float*     Cbuf   = (float*)(wsb + 85327872);         //    262,144 B
    float*     Ssum   = (float*)(wsb + 85590016);         //  1,048,576 B
    float*     hloc   = (float*)(wsb + 86638592);         // 16,777,216 B
    float*     h0buf  = (float*)(wsb + 103415808);        // 16,777,216 B
    _Float16*  WoutT  = (_Float16*)(wsb + 120193024);     //  4,194,304 B
    float*     cwT    = (float*)(wsb + 124387328);        //     32,768 B
    // end: 124,420,096 B

    dim3 blk(256);

    // 1. fused prep: all weight transposes + x cast + conv_w transpose
    prep<<<dim3(10561), blk, 0, stream>>>(x, xf16, W_in, WinT, W_x, WxT,
                                          W_dt, WdtT, W_out, WoutT, conv_w, cwT);
    // 2. K1: [xs fp16 | silu(res) fp16] = x @ W_in  (M=4096, N=4096, K=1024)
    gemm_k1<<<dim3(16, 16), dim3(512), 0, stream>>>(xf16, WinT, xsh, sresh);
    // 3. conv + SiLU -> xch fp16  (coalesced cwT weights)
    conv_silu<<<dim3((size_t)MM * D_INNER / 8 / 256), blk, 0, stream>>>(xsh, cwT, conv_b, xch);
    // 4. fused xd + delta: Bm/Cm fp32 + deltah fp16
    gemm_xd_delta<<<dim3(MM / 16), blk, 0, stream>>>(xch, WxT, WdtT, b_dt, Bbuf, Cbuf, deltah);
    // 5. scan pass 1  (R14: 2 channels/thread -> grid x = D_INNER/512)
    scan_part1<<<dim3(D_INNER / 512, NCH, B_SZ), blk, 0, stream>>>(deltah, xch, Bbuf, A_log, hloc, Ssum);
    // 6. combine
    scan_combine<<<dim3(B_SZ * D_INNER * 16 / 256), blk, 0, stream>>>(hloc, Ssum, A_log, h0buf);
    // 7. scan pass 2 (R14: 2 channels/thread) -> yhalf fp16
    scan_part2<<<dim3(D_INNER / 512, NCH, B_SZ), blk, 0, stream>>>(deltah, xch, Bbuf, Cbuf, h0buf, A_log, D_par, sresh, yhalf);
    // 8. K5: out = y @ W_out  (M=4096, N=1024, K=2048)
    gemm_f16<0><<<dim3(8, 32), blk, 0, stream>>>(
        yhalf, WoutT, nullptr, out, nullptr, nullptr, MM, D_MODEL, D_INNER, D_MODEL);
}